// Round 1
// baseline (3479.173 us; speedup 1.0000x reference)
//
#include <hip/hip_runtime.h>

#define BB 8
#define CINC 64
#define COUTC 64
#define GCC 64
#define HH 320
#define WW 320
#define HP 322          // H + 2*P (padded/conv-output spatial)
#define WP 322
#define LEAK 0.2f
#define EPSB 1e-5f
#define HWSZ (HH*WW)    // 102400
#define HWPSZ (HP*WP)   // 103684

// ---------------- K1: per-(b,g) mean of guidance ----------------
__global__ __launch_bounds__(256) void k_mean(const float* __restrict__ g,
                                              float* __restrict__ mean_g) {
    int row = blockIdx.x;                       // b*GC + gc
    const float4* p = (const float4*)(g + (size_t)row * HWSZ);
    float s = 0.f;
    for (int i = threadIdx.x; i < HWSZ / 4; i += 256) {
        float4 v = p[i];
        s += v.x + v.y + v.z + v.w;
    }
    #pragma unroll
    for (int off = 32; off; off >>= 1) s += __shfl_down(s, off);
    __shared__ float ls[4];
    if ((threadIdx.x & 63) == 0) ls[threadIdx.x >> 6] = s;
    __syncthreads();
    if (threadIdx.x == 0)
        mean_g[row] = (ls[0] + ls[1] + ls[2] + ls[3]) * (1.f / (float)HWSZ);
}

// ---------------- K2: kcc[b,o,c] = mean_g[b,:] @ w_cc[o*64+c,:] + b_cc ----
// stored TRANSPOSED as kccT[b][c][o] so k_main can scalar-load 64 contiguous o
__global__ __launch_bounds__(256) void k_kcc(const float* __restrict__ mean_g,
                                             const float* __restrict__ w_cc,
                                             const float* __restrict__ b_cc,
                                             float* __restrict__ kccT) {
    int idx = blockIdx.x * 256 + threadIdx.x;   // b*4096 + o*64 + c
    if (idx >= BB * COUTC * CINC) return;
    int b = idx >> 12;
    int j = idx & 4095;                          // o*64 + c
    int o = j >> 6, c = j & 63;
    const float* mg = mean_g + b * GCC;
    const float* wr = w_cc + (size_t)j * GCC;
    float s = b_cc[j];
    #pragma unroll
    for (int g = 0; g < GCC; ++g) s += mg[g] * wr[g];
    kccT[((size_t)b * CINC + c) * COUTC + o] = s;
}

// ---------------- K3: kernel-map conv (guidance * w_kgl, pad=2) ----------
// block = 256 threads = 16x16 output pixels, computes ALL 64 out channels.
// guidance staged in LDS in 16-channel chunks; weights via uniform s_loads.
#define CT 16
#define TXN 21          // ceil(322/16)
__global__ __launch_bounds__(256) void k_conv(const float* __restrict__ guid,
                                              const float* __restrict__ w_kgl,
                                              const float* __restrict__ b_kgl,
                                              float* __restrict__ ker,
                                              int b0) {
    int tile = blockIdx.x;
    int b = b0 + blockIdx.y;
    int ty0 = (tile / TXN) * CT, tx0 = (tile % TXN) * CT;
    int ty = threadIdx.x >> 4, tx = threadIdx.x & 15;
    int oy = ty0 + ty, ox = tx0 + tx;

    __shared__ float gt[16][18 * 18];
    float acc[CINC];
    #pragma unroll
    for (int c = 0; c < CINC; ++c) acc[c] = 0.f;

    const float* gb = guid + (size_t)b * GCC * HWSZ;
    for (int gc = 0; gc < GCC; gc += 16) {
        for (int i = threadIdx.x; i < 16 * 324; i += 256) {
            int gg = i / 324;
            int rem = i - gg * 324;
            int r = rem / 18, cc = rem - r * 18;
            int iy = ty0 - 2 + r, ix = tx0 - 2 + cc;
            float v = 0.f;
            if (iy >= 0 && iy < HH && ix >= 0 && ix < WW)
                v = gb[(size_t)(gc + gg) * HWSZ + iy * WW + ix];
            gt[gg][rem] = v;
        }
        __syncthreads();
        for (int gg = 0; gg < 16; ++gg) {
            float gv[9];
            #pragma unroll
            for (int d = 0; d < 9; ++d) {
                int di = d / 3, dj = d % 3;
                gv[d] = gt[gg][(ty + di) * 18 + (tx + dj)];
            }
            const float* wb = w_kgl + (size_t)(gc + gg) * 9;
            #pragma unroll
            for (int c = 0; c < CINC; ++c) {
                const float* wc = wb + (size_t)c * GCC * 9;   // uniform -> s_load
                #pragma unroll
                for (int d = 0; d < 9; ++d) acc[c] += gv[d] * wc[d];
            }
        }
        __syncthreads();
    }
    if (oy < HP && ox < WP) {
        float* kerb = ker + (size_t)blockIdx.y * CINC * HWPSZ;
        #pragma unroll
        for (int c = 0; c < CINC; ++c)
            kerb[(size_t)c * HWPSZ + oy * WP + ox] = acc[c] + b_kgl[c];
    }
}

// ---------------- K4: guided box-sum + channel mix + leaky, x3 -> d_out ---
__global__ __launch_bounds__(256) void k_main(const float* __restrict__ data,
                                              const float* __restrict__ ker,
                                              const float* __restrict__ kccT,
                                              float* __restrict__ x3out,
                                              int b0) {
    int b = b0 + blockIdx.y;
    int px = blockIdx.x * 256 + threadIdx.x;
    int h = px / WW, w = px - h * WW;
    const float* dbase = data + (size_t)b * CINC * HWSZ;
    const float* kerb  = ker + (size_t)blockIdx.y * CINC * HWPSZ;
    const float* kb    = kccT + (size_t)b * CINC * COUTC;

    float acc[COUTC];
    #pragma unroll
    for (int o = 0; o < COUTC; ++o) acc[o] = 0.f;

    for (int c = 0; c < CINC; ++c) {
        const float* kc = kerb + (size_t)c * HWPSZ;
        const float* dc = dbase + (size_t)c * HWSZ;
        float x1 = 0.f;
        #pragma unroll
        for (int dy = 0; dy < 3; ++dy) {
            int u = h + dy;          // padded-row coord in [0,322)
            int iu = u - 1;          // data row
            bool rok = (iu >= 0) & (iu < HH);
            #pragma unroll
            for (int dx = 0; dx < 3; ++dx) {
                int v = w + dx, iv = v - 1;
                float kv = kc[u * WP + v];
                float dv = (rok && iv >= 0 && iv < WW) ? dc[iu * WW + iv] : 0.f;
                x1 += kv * dv;
            }
        }
        const float* ko = kb + (size_t)c * COUTC;   // uniform -> s_load x16
        #pragma unroll
        for (int o = 0; o < COUTC; ++o) acc[o] += ko[o] * x1;
    }
    #pragma unroll
    for (int o = 0; o < COUTC; ++o) {
        float v = acc[o];
        v = v > 0.f ? v : LEAK * v;
        x3out[((size_t)b * COUTC + o) * HWSZ + px] = v;
    }
}

// ---------------- K5a: batchnorm statistics over d_out -------------------
__global__ __launch_bounds__(256) void k_stats(const float* __restrict__ x,
                                               float* __restrict__ sums,
                                               float* __restrict__ sumsq) {
    int row = blockIdx.x;            // b*COUT + o
    int o = row & 63;
    const float4* p = (const float4*)(x + (size_t)row * HWSZ);
    float s = 0.f, q = 0.f;
    for (int i = threadIdx.x; i < HWSZ / 4; i += 256) {
        float4 v = p[i];
        s += v.x + v.y + v.z + v.w;
        q += v.x * v.x + v.y * v.y + v.z * v.z + v.w * v.w;
    }
    #pragma unroll
    for (int off = 32; off; off >>= 1) { s += __shfl_down(s, off); q += __shfl_down(q, off); }
    __shared__ float ls[8];
    if ((threadIdx.x & 63) == 0) { ls[(threadIdx.x >> 6) * 2] = s; ls[(threadIdx.x >> 6) * 2 + 1] = q; }
    __syncthreads();
    if (threadIdx.x == 0) {
        s = ls[0] + ls[2] + ls[4] + ls[6];
        q = ls[1] + ls[3] + ls[5] + ls[7];
        atomicAdd(&sums[o], s);
        atomicAdd(&sumsq[o], q);
    }
}

// ---------------- K5b: finalize scale/shift ------------------------------
__global__ void k_fin(const float* __restrict__ sums, const float* __restrict__ sumsq,
                      const float* __restrict__ gamma, const float* __restrict__ beta,
                      float* __restrict__ scale, float* __restrict__ shift) {
    int o = threadIdx.x;
    float n = (float)BB * (float)HWSZ;
    float mu = sums[o] / n;
    float var = sumsq[o] / n - mu * mu;
    float rs = rsqrtf(var + EPSB);
    float sc = rs * gamma[o];
    scale[o] = sc;
    shift[o] = beta[o] - mu * sc;
}

// ---------------- K6: in-place normalize ---------------------------------
__global__ __launch_bounds__(256) void k_norm(float* __restrict__ x,
                                              const float* __restrict__ scale,
                                              const float* __restrict__ shift) {
    size_t i = (size_t)blockIdx.x * 256 + threadIdx.x;   // float4 index
    int ch = (int)((i * 4) / HWSZ) & 63;
    float4 v = ((float4*)x)[i];
    float sc = scale[ch], sh = shift[ch];
    v.x = v.x * sc + sh; v.y = v.y * sc + sh; v.z = v.z * sc + sh; v.w = v.w * sc + sh;
    ((float4*)x)[i] = v;
}

extern "C" void kernel_launch(void* const* d_in, const int* in_sizes, int n_in,
                              void* d_out, int out_size, void* d_ws, size_t ws_size,
                              hipStream_t stream) {
    const float* data  = (const float*)d_in[0];
    const float* guid  = (const float*)d_in[1];
    const float* w_kgl = (const float*)d_in[2];
    const float* b_kgl = (const float*)d_in[3];
    const float* w_cc  = (const float*)d_in[4];
    const float* b_cc  = (const float*)d_in[5];
    const float* gamma = (const float*)d_in[6];
    const float* beta  = (const float*)d_in[7];
    float* out = (float*)d_out;
    float* ws  = (float*)d_ws;

    // ws layout (floats): [mean_g 512][kccT 32768][sums 64][sumsq 64][scale 64][shift 64][ker ...]
    float* mean_g = ws;
    float* kccT   = ws + 512;
    float* sums   = ws + 512 + 32768;
    float* sumsq  = sums + 64;
    float* scale  = sumsq + 64;
    float* shift  = scale + 64;
    float* ker    = shift + 64;
    size_t smalls = 512 + 32768 + 256;
    size_t cap    = (ws_size / 4 > smalls) ? ws_size / 4 - smalls : 0;

    // batch-chunk the kernel-map buffer: bs in {4,2,1}
    int bs = 4;
    while (bs > 1 && (size_t)bs * CINC * HWPSZ > cap) bs >>= 1;

    k_mean<<<BB * GCC, 256, 0, stream>>>(guid, mean_g);
    k_kcc<<<(BB * COUTC * CINC + 255) / 256, 256, 0, stream>>>(mean_g, w_cc, b_cc, kccT);
    hipMemsetAsync(sums, 0, 2 * 64 * sizeof(float), stream);

    for (int b0 = 0; b0 < BB; b0 += bs) {
        k_conv<<<dim3(TXN * TXN, bs), 256, 0, stream>>>(guid, w_kgl, b_kgl, ker, b0);
        k_main<<<dim3(HWSZ / 256, bs), 256, 0, stream>>>(data, ker, kccT, out, b0);
    }
    k_stats<<<BB * COUTC, 256, 0, stream>>>(out, sums, sumsq);
    k_fin<<<1, 64, 0, stream>>>(sums, sumsq, gamma, beta, scale, shift);
    k_norm<<<(out_size / 4 + 255) / 256, 256, 0, stream>>>(out, scale, shift);
}

// Round 2
// 1149.407 us; speedup vs baseline: 3.0269x; 3.0269x over previous
//
#include <hip/hip_runtime.h>

#define BB 8
#define CINC 64
#define COUTC 64
#define GCC 64
#define HH 320
#define WW 320
#define HP 322
#define WP 322
#define LEAK 0.2f
#define EPSB 1e-5f
#define HWSZ (HH*WW)
#define HWPSZ (HP*WP)

typedef unsigned short u16;
typedef __attribute__((ext_vector_type(8))) short short8v;   // 8 bf16 (4 VGPR)
typedef __attribute__((ext_vector_type(16))) float f32x16;   // MFMA 32x32 acc
typedef __attribute__((ext_vector_type(4))) unsigned int u32x4;

static __device__ __forceinline__ u16 f2bf(float f) {
    unsigned u = __float_as_uint(f);
    u += 0x7fffu + ((u >> 16) & 1u);      // RNE
    return (u16)(u >> 16);
}
static __device__ __forceinline__ float bf2f(u16 h) {
    return __uint_as_float((unsigned)h << 16);
}

// ---------------- K1: per-(b,g) mean of guidance ----------------
__global__ __launch_bounds__(256) void k_mean(const float* __restrict__ g,
                                              float* __restrict__ mean_g) {
    int row = blockIdx.x;
    const float4* p = (const float4*)(g + (size_t)row * HWSZ);
    float s = 0.f;
    for (int i = threadIdx.x; i < HWSZ / 4; i += 256) {
        float4 v = p[i];
        s += v.x + v.y + v.z + v.w;
    }
    #pragma unroll
    for (int off = 32; off; off >>= 1) s += __shfl_down(s, off);
    __shared__ float ls[4];
    if ((threadIdx.x & 63) == 0) ls[threadIdx.x >> 6] = s;
    __syncthreads();
    if (threadIdx.x == 0)
        mean_g[row] = (ls[0] + ls[1] + ls[2] + ls[3]) * (1.f / (float)HWSZ);
}

// ---------------- K2: kccT[b][c][o] ----------------
__global__ __launch_bounds__(256) void k_kcc(const float* __restrict__ mean_g,
                                             const float* __restrict__ w_cc,
                                             const float* __restrict__ b_cc,
                                             float* __restrict__ kccT) {
    int idx = blockIdx.x * 256 + threadIdx.x;
    if (idx >= BB * COUTC * CINC) return;
    int b = idx >> 12;
    int j = idx & 4095;                  // o*64 + c
    int o = j >> 6, c = j & 63;
    const float* mg = mean_g + b * GCC;
    const float* wr = w_cc + (size_t)j * GCC;
    float s = b_cc[j];
    #pragma unroll
    for (int g = 0; g < GCC; ++g) s += mg[g] * wr[g];
    kccT[((size_t)b * CINC + c) * COUTC + o] = s;
}

// ---------------- K3: wB[tap][cout][g] bf16 from w_kgl[cout][g][3][3] -----
__global__ __launch_bounds__(256) void k_wb(const float* __restrict__ w_kgl,
                                            u16* __restrict__ wB) {
    int i = blockIdx.x * 256 + threadIdx.x;      // tap*4096 + o*64 + g
    if (i >= 9 * 4096) return;
    int tap = i >> 12, o = (i >> 6) & 63, g = i & 63;
    wB[i] = f2bf(w_kgl[((size_t)(o * 64 + g)) * 9 + tap]);
}

// ---------------- K4: transpose guidance -> guidT bf16 [bi][h][w][g] ------
__global__ __launch_bounds__(256) void k_tr(const float* __restrict__ guid,
                                            u16* __restrict__ guidT, int b0) {
    int w0 = blockIdx.x * 64;
    int h  = blockIdx.y;
    int bi = blockIdx.z;
    int bg = b0 + bi;
    int tid = threadIdx.x;
    __shared__ u16 tile[64][68];
    const float* src = guid + ((size_t)bg * GCC) * HWSZ + (size_t)h * WW + w0;
    #pragma unroll
    for (int k = 0; k < 4; ++k) {
        int i = tid + k * 256;               // g*16 + wq
        int g = i >> 4, wq = i & 15;
        float4 v = *(const float4*)(src + (size_t)g * HWSZ + wq * 4);
        tile[g][wq * 4 + 0] = f2bf(v.x);
        tile[g][wq * 4 + 1] = f2bf(v.y);
        tile[g][wq * 4 + 2] = f2bf(v.z);
        tile[g][wq * 4 + 3] = f2bf(v.w);
    }
    __syncthreads();
    u16* dst = guidT + (((size_t)bi * HH + h) * WW + w0) * GCC;
    #pragma unroll
    for (int k = 0; k < 2; ++k) {
        int i = tid + k * 256;               // w*8 + g8
        int w = i >> 3, g8 = i & 7;
        union { u16 s[8]; u32x4 v; } t;
        #pragma unroll
        for (int j = 0; j < 8; ++j) t.s[j] = tile[g8 * 8 + j][w];
        *(u32x4*)(dst + (size_t)w * GCC + g8 * 8) = t.v;
    }
}

// ---------------- K5: MFMA conv -> ker bf16 [bi][py*WP+px][cout] ----------
// block 384 thr (6 waves), tile = 6 output rows x 64 cols x 64 couts.
// wave = 1 output row; mfma 32x32x16; LDS staged ONCE (8 rows x 66 x 64 g).
__global__ __launch_bounds__(384) void k_convm(const u16* __restrict__ guidT,
                                               const u16* __restrict__ wB,
                                               const float* __restrict__ b_kgl,
                                               u16* __restrict__ ker) {
    int xt = blockIdx.x, rt = blockIdx.y, bi = blockIdx.z;
    int tid = threadIdx.x;
    int x0 = xt * 64, oy0 = rt * 6;
    __shared__ __align__(16) u16 lds[8 * 66 * 64];

    const u16* gsrc = guidT + (size_t)bi * HH * WW * GCC;
    for (int i = tid; i < 8 * 66 * 8; i += 384) {
        int rr = i / 528, rem = i - rr * 528;
        int cc = rem >> 3, u8 = rem & 7;
        int iy = oy0 - 2 + rr, ix = x0 - 2 + cc;
        u32x4 val = {0, 0, 0, 0};
        if (iy >= 0 && iy < HH && ix >= 0 && ix < WW)
            val = *(const u32x4*)(gsrc + ((size_t)iy * WW + ix) * GCC + u8 * 8);
        unsigned off = ((unsigned)(rr * 66 + cc) * 128u + (unsigned)u8 * 16u)
                       ^ ((unsigned)(cc & 7) << 4);
        *(u32x4*)((char*)lds + off) = val;
    }
    __syncthreads();

    int wv = tid >> 6, lane = tid & 63;
    int l31 = lane & 31, lhi = lane >> 5;
    f32x16 acc[2][2] = {};

    for (int tap = 0; tap < 9; ++tap) {          // runtime loop: keep B live-range short
        int di = tap / 3, dj = tap - di * 3;
        short8v B[4][2];
        #pragma unroll
        for (int ks = 0; ks < 4; ++ks)
            #pragma unroll
            for (int nj = 0; nj < 2; ++nj)
                B[ks][nj] = *(const short8v*)(wB +
                    ((size_t)(tap * 64 + nj * 32 + l31) * 64 + ks * 16 + lhi * 8));
        int rrow = wv + di;
        #pragma unroll
        for (int ks = 0; ks < 4; ++ks)
            #pragma unroll
            for (int s = 0; s < 2; ++s) {
                int cc = s * 32 + l31 + dj;
                unsigned off = ((unsigned)(rrow * 66 + cc) * 128u +
                                (unsigned)(ks * 32 + lhi * 16))
                               ^ ((unsigned)(cc & 7) << 4);
                short8v a = *(const short8v*)((const char*)lds + off);
                acc[s][0] = __builtin_amdgcn_mfma_f32_32x32x16_bf16(a, B[ks][0], acc[s][0], 0, 0, 0);
                acc[s][1] = __builtin_amdgcn_mfma_f32_32x32x16_bf16(a, B[ks][1], acc[s][1], 0, 0, 0);
            }
    }

    int oy = oy0 + wv;
    if (oy < HP) {
        float bias0 = b_kgl[l31], bias1 = b_kgl[32 + l31];
        u16* kout = ker + (size_t)bi * HWPSZ * GCC;
        #pragma unroll
        for (int s = 0; s < 2; ++s)
            #pragma unroll
            for (int r = 0; r < 16; ++r) {
                int pxc = x0 + s * 32 + (r & 3) + 8 * (r >> 2) + 4 * lhi;
                if (pxc < WP) {
                    size_t base = ((size_t)oy * WP + pxc) * GCC;
                    kout[base + l31]      = f2bf(acc[s][0][r] + bias0);
                    kout[base + 32 + l31] = f2bf(acc[s][1][r] + bias1);
                }
            }
    }
}

// ---------------- K6: box-sum * data + channel mix + leaky ----------------
__global__ __launch_bounds__(256) void k_main(const float* __restrict__ data,
                                              const u16* __restrict__ ker,
                                              const float* __restrict__ kccT,
                                              float* __restrict__ out, int b0) {
    int bi = blockIdx.y, b = b0 + bi;
    int px = blockIdx.x * 256 + threadIdx.x;
    int h = px / WW, w = px - h * WW;
    const u16* kerb = ker + (size_t)bi * HWPSZ * GCC;
    const float* dbase = data + (size_t)b * CINC * HWSZ;
    const float* kb = kccT + (size_t)b * CINC * COUTC;

    float acc[COUTC];
    #pragma unroll
    for (int o = 0; o < COUTC; ++o) acc[o] = 0.f;

    for (int c0 = 0; c0 < CINC; c0 += 16) {      // c-chunks keep regs bounded
        float x1c[16];
        #pragma unroll
        for (int j = 0; j < 16; ++j) x1c[j] = 0.f;
        #pragma unroll
        for (int t = 0; t < 9; ++t) {
            const int di = t / 3, dj = t % 3;
            int u = h + di, v = w + dj;
            int iu = u - 1, iv = v - 1;
            if (iu >= 0 && iu < HH && iv >= 0 && iv < WW) {
                const u16* krow = kerb + ((size_t)u * WP + v) * GCC + c0;
                const float* dc = dbase + (size_t)iu * WW + iv + (size_t)c0 * HWSZ;
                u32x4 kv0 = *(const u32x4*)(krow);
                u32x4 kv1 = *(const u32x4*)(krow + 8);
                const u16* ks0 = (const u16*)&kv0;
                const u16* ks1 = (const u16*)&kv1;
                #pragma unroll
                for (int j = 0; j < 8; ++j) {
                    x1c[j]     += bf2f(ks0[j]) * dc[(size_t)j * HWSZ];
                    x1c[8 + j] += bf2f(ks1[j]) * dc[(size_t)(8 + j) * HWSZ];
                }
            }
        }
        #pragma unroll
        for (int j = 0; j < 16; ++j) {
            float xc = x1c[j];
            const float* ko = kb + (size_t)(c0 + j) * COUTC;
            #pragma unroll
            for (int o = 0; o < COUTC; ++o) acc[o] += ko[o] * xc;
        }
    }
    #pragma unroll
    for (int o = 0; o < COUTC; ++o) {
        float v = acc[o];
        v = v > 0.f ? v : LEAK * v;
        out[((size_t)b * COUTC + o) * HWSZ + px] = v;
    }
}

// ---------------- K7: batchnorm stats ----------------
__global__ __launch_bounds__(256) void k_stats(const float* __restrict__ x,
                                               float* __restrict__ sums,
                                               float* __restrict__ sumsq) {
    int row = blockIdx.x;
    int o = row & 63;
    const float4* p = (const float4*)(x + (size_t)row * HWSZ);
    float s = 0.f, q = 0.f;
    for (int i = threadIdx.x; i < HWSZ / 4; i += 256) {
        float4 v = p[i];
        s += v.x + v.y + v.z + v.w;
        q += v.x * v.x + v.y * v.y + v.z * v.z + v.w * v.w;
    }
    #pragma unroll
    for (int off = 32; off; off >>= 1) { s += __shfl_down(s, off); q += __shfl_down(q, off); }
    __shared__ float ls[8];
    if ((threadIdx.x & 63) == 0) { ls[(threadIdx.x >> 6) * 2] = s; ls[(threadIdx.x >> 6) * 2 + 1] = q; }
    __syncthreads();
    if (threadIdx.x == 0) {
        s = ls[0] + ls[2] + ls[4] + ls[6];
        q = ls[1] + ls[3] + ls[5] + ls[7];
        atomicAdd(&sums[o], s);
        atomicAdd(&sumsq[o], q);
    }
}

__global__ void k_fin(const float* __restrict__ sums, const float* __restrict__ sumsq,
                      const float* __restrict__ gamma, const float* __restrict__ beta,
                      float* __restrict__ scale, float* __restrict__ shift) {
    int o = threadIdx.x;
    float n = (float)BB * (float)HWSZ;
    float mu = sums[o] / n;
    float var = sumsq[o] / n - mu * mu;
    float rs = rsqrtf(var + EPSB);
    float sc = rs * gamma[o];
    scale[o] = sc;
    shift[o] = beta[o] - mu * sc;
}

__global__ __launch_bounds__(256) void k_norm(float* __restrict__ x,
                                              const float* __restrict__ scale,
                                              const float* __restrict__ shift) {
    size_t i = (size_t)blockIdx.x * 256 + threadIdx.x;
    int ch = (int)((i * 4) / HWSZ) & 63;
    float4 v = ((float4*)x)[i];
    float sc = scale[ch], sh = shift[ch];
    v.x = v.x * sc + sh; v.y = v.y * sc + sh; v.z = v.z * sc + sh; v.w = v.w * sc + sh;
    ((float4*)x)[i] = v;
}

extern "C" void kernel_launch(void* const* d_in, const int* in_sizes, int n_in,
                              void* d_out, int out_size, void* d_ws, size_t ws_size,
                              hipStream_t stream) {
    const float* data  = (const float*)d_in[0];
    const float* guid  = (const float*)d_in[1];
    const float* w_kgl = (const float*)d_in[2];
    const float* b_kgl = (const float*)d_in[3];
    const float* w_cc  = (const float*)d_in[4];
    const float* b_cc  = (const float*)d_in[5];
    const float* gamma = (const float*)d_in[6];
    const float* beta  = (const float*)d_in[7];
    float* out = (float*)d_out;
    float* ws  = (float*)d_ws;

    // ws layout: [mean_g 512][kccT 32768][sums 64][sumsq 64][scale 64][shift 64]
    //            [wB 36864 u16][guidT bs*320*320*64 u16][ker bs*HWPSZ*64 u16]
    float* mean_g = ws;
    float* kccT   = ws + 512;
    float* sums   = ws + 512 + 32768;
    float* sumsq  = sums + 64;
    float* scale  = sumsq + 64;
    float* shift  = scale + 64;
    u16*   wB     = (u16*)(shift + 64);
    u16*   guidT  = wB + 9 * 4096;

    size_t used_us = (size_t)(512 + 32768 + 256) * 2 + 9 * 4096;
    size_t cap_us  = (ws_size / 2 > used_us) ? ws_size / 2 - used_us : 0;
    size_t per_b   = (size_t)HH * WW * GCC + (size_t)HWPSZ * GCC;
    int bs = 8;
    while (bs > 1 && (size_t)bs * per_b > cap_us) bs >>= 1;
    u16* kerb = guidT + (size_t)bs * HH * WW * GCC;

    k_mean<<<BB * GCC, 256, 0, stream>>>(guid, mean_g);
    k_kcc<<<(BB * COUTC * CINC + 255) / 256, 256, 0, stream>>>(mean_g, w_cc, b_cc, kccT);
    k_wb<<<(9 * 4096 + 255) / 256, 256, 0, stream>>>(w_kgl, wB);
    hipMemsetAsync(sums, 0, 2 * 64 * sizeof(float), stream);

    for (int b0 = 0; b0 < BB; b0 += bs) {
        int nb = (BB - b0 < bs) ? BB - b0 : bs;
        k_tr<<<dim3(WW / 64, HH, nb), 256, 0, stream>>>(guid, guidT, b0);
        k_convm<<<dim3(6, 54, nb), 384, 0, stream>>>(guidT, wB, b_kgl, kerb);
        k_main<<<dim3(HWSZ / 256, nb), 256, 0, stream>>>(data, kerb, kccT, out, b0);
    }
    k_stats<<<BB * COUTC, 256, 0, stream>>>(out, sums, sumsq);
    k_fin<<<1, 64, 0, stream>>>(sums, sumsq, gamma, beta, scale, shift);
    k_norm<<<(out_size / 4 + 255) / 256, 256, 0, stream>>>(out, scale, shift);
}

// Round 4
// 792.682 us; speedup vs baseline: 4.3891x; 1.4500x over previous
//
#include <hip/hip_runtime.h>

#define BB 8
#define CINC 64
#define COUTC 64
#define GCC 64
#define HH 320
#define WW 320
#define HP 322
#define WP 322
#define LEAK 0.2f
#define EPSB 1e-5f
#define HWSZ (HH*WW)
#define HWPSZ (HP*WP)

typedef unsigned short u16;
typedef __attribute__((ext_vector_type(8))) short short8v;   // 8 bf16
typedef __attribute__((ext_vector_type(16))) float f32x16;   // MFMA 32x32 acc
typedef __attribute__((ext_vector_type(4))) unsigned int u32x4;

static __device__ __forceinline__ u16 f2bf(float f) {
    unsigned u = __float_as_uint(f);
    u += 0x7fffu + ((u >> 16) & 1u);      // RNE
    return (u16)(u >> 16);
}

// ---------------- K1: per-(b,g) mean of guidance ----------------
__global__ __launch_bounds__(256) void k_mean(const float* __restrict__ g,
                                              float* __restrict__ mean_g) {
    int row = blockIdx.x;
    const float4* p = (const float4*)(g + (size_t)row * HWSZ);
    float s = 0.f;
    for (int i = threadIdx.x; i < HWSZ / 4; i += 256) {
        float4 v = p[i];
        s += v.x + v.y + v.z + v.w;
    }
    #pragma unroll
    for (int off = 32; off; off >>= 1) s += __shfl_down(s, off);
    __shared__ float ls[4];
    if ((threadIdx.x & 63) == 0) ls[threadIdx.x >> 6] = s;
    __syncthreads();
    if (threadIdx.x == 0)
        mean_g[row] = (ls[0] + ls[1] + ls[2] + ls[3]) * (1.f / (float)HWSZ);
}

// ---------------- K2: kccB[b][o][c] bf16 ----------------
__global__ __launch_bounds__(256) void k_kcc(const float* __restrict__ mean_g,
                                             const float* __restrict__ w_cc,
                                             const float* __restrict__ b_cc,
                                             u16* __restrict__ kccB) {
    int idx = blockIdx.x * 256 + threadIdx.x;
    if (idx >= BB * COUTC * CINC) return;
    int b = idx >> 12;
    int j = idx & 4095;                  // o*64 + c
    const float* mg = mean_g + b * GCC;
    const float* wr = w_cc + (size_t)j * GCC;
    float s = b_cc[j];
    #pragma unroll
    for (int g = 0; g < GCC; ++g) s += mg[g] * wr[g];
    kccB[idx] = f2bf(s);
}

// ---------------- K3: wB[tap][cout][g] bf16 ----------------
__global__ __launch_bounds__(256) void k_wb(const float* __restrict__ w_kgl,
                                            u16* __restrict__ wB) {
    int i = blockIdx.x * 256 + threadIdx.x;      // tap*4096 + o*64 + g
    if (i >= 9 * 4096) return;
    int tap = i >> 12, o = (i >> 6) & 63, g = i & 63;
    wB[i] = f2bf(w_kgl[((size_t)(o * 64 + g)) * 9 + tap]);
}

// ---------------- K4: transpose guidance -> guidT bf16 [bi][h][w][g] ------
__global__ __launch_bounds__(256) void k_tr(const float* __restrict__ guid,
                                            u16* __restrict__ guidT, int b0) {
    int w0 = blockIdx.x * 64;
    int h  = blockIdx.y;
    int bi = blockIdx.z;
    int bg = b0 + bi;
    int tid = threadIdx.x;
    __shared__ u16 tile[64][68];
    const float* src = guid + ((size_t)bg * GCC) * HWSZ + (size_t)h * WW + w0;
    #pragma unroll
    for (int k = 0; k < 4; ++k) {
        int i = tid + k * 256;               // g*16 + wq
        int g = i >> 4, wq = i & 15;
        float4 v = *(const float4*)(src + (size_t)g * HWSZ + wq * 4);
        tile[g][wq * 4 + 0] = f2bf(v.x);
        tile[g][wq * 4 + 1] = f2bf(v.y);
        tile[g][wq * 4 + 2] = f2bf(v.z);
        tile[g][wq * 4 + 3] = f2bf(v.w);
    }
    __syncthreads();
    u16* dst = guidT + (((size_t)bi * HH + h) * WW + w0) * GCC;
    #pragma unroll
    for (int k = 0; k < 2; ++k) {
        int i = tid + k * 256;               // w*8 + g8
        int w = i >> 3, g8 = i & 7;
        union { u16 s[8]; u32x4 v; } t;
        #pragma unroll
        for (int j = 0; j < 8; ++j) t.s[j] = tile[g8 * 8 + j][w];
        *(u32x4*)(dst + (size_t)w * GCC + g8 * 8) = t.v;
    }
}

// ---------------- K5: MFMA conv -> ker bf16 [bi][py*WP+px][c] -------------
__global__ __launch_bounds__(384) void k_convm(const u16* __restrict__ guidT,
                                               const u16* __restrict__ wB,
                                               const float* __restrict__ b_kgl,
                                               u16* __restrict__ ker) {
    int xt = blockIdx.x, rt = blockIdx.y, bi = blockIdx.z;
    int tid = threadIdx.x;
    int x0 = xt * 64, oy0 = rt * 6;
    __shared__ __align__(16) u16 lds[8 * 66 * 64];

    const u16* gsrc = guidT + (size_t)bi * HH * WW * GCC;
    for (int i = tid; i < 8 * 66 * 8; i += 384) {
        int rr = i / 528, rem = i - rr * 528;
        int cc = rem >> 3, u8 = rem & 7;
        int iy = oy0 - 2 + rr, ix = x0 - 2 + cc;
        u32x4 val = {0, 0, 0, 0};
        if (iy >= 0 && iy < HH && ix >= 0 && ix < WW)
            val = *(const u32x4*)(gsrc + ((size_t)iy * WW + ix) * GCC + u8 * 8);
        unsigned off = ((unsigned)(rr * 66 + cc) * 128u + (unsigned)u8 * 16u)
                       ^ ((unsigned)(cc & 7) << 4);
        *(u32x4*)((char*)lds + off) = val;
    }
    __syncthreads();

    int wv = tid >> 6, lane = tid & 63;
    int l31 = lane & 31, lhi = lane >> 5;
    f32x16 acc[2][2] = {};

    for (int tap = 0; tap < 9; ++tap) {
        int di = tap / 3, dj = tap - di * 3;
        short8v B[4][2];
        #pragma unroll
        for (int ks = 0; ks < 4; ++ks)
            #pragma unroll
            for (int nj = 0; nj < 2; ++nj)
                B[ks][nj] = *(const short8v*)(wB +
                    ((size_t)(tap * 64 + nj * 32 + l31) * 64 + ks * 16 + lhi * 8));
        int rrow = wv + di;
        #pragma unroll
        for (int ks = 0; ks < 4; ++ks)
            #pragma unroll
            for (int s = 0; s < 2; ++s) {
                int cc = s * 32 + l31 + dj;
                unsigned off = ((unsigned)(rrow * 66 + cc) * 128u +
                                (unsigned)(ks * 32 + lhi * 16))
                               ^ ((unsigned)(cc & 7) << 4);
                short8v a = *(const short8v*)((const char*)lds + off);
                acc[s][0] = __builtin_amdgcn_mfma_f32_32x32x16_bf16(a, B[ks][0], acc[s][0], 0, 0, 0);
                acc[s][1] = __builtin_amdgcn_mfma_f32_32x32x16_bf16(a, B[ks][1], acc[s][1], 0, 0, 0);
            }
    }

    int oy = oy0 + wv;
    if (oy < HP) {
        float bias0 = b_kgl[l31], bias1 = b_kgl[32 + l31];
        u16* kout = ker + (size_t)bi * HWPSZ * GCC;
        #pragma unroll
        for (int s = 0; s < 2; ++s)
            #pragma unroll
            for (int r = 0; r < 16; ++r) {
                int pxc = x0 + s * 32 + (r & 3) + 8 * (r >> 2) + 4 * lhi;
                if (pxc < WP) {
                    size_t base = ((size_t)oy * WP + pxc) * GCC;
                    kout[base + l31]      = f2bf(acc[s][0][r] + bias0);
                    kout[base + 32 + l31] = f2bf(acc[s][1][r] + bias1);
                }
            }
    }
}

// ---------------- K6: k_mix — box-sum + MFMA channel mix + leaky ----------
// block 384 thr (6 waves), tile = 6 out rows x 64 px x 64 o.
// A = kcc (M=o), B = x1 frag (N=px) -> D px-major, coalesced stores.
// data staged per 16-c chunk in LDS planes [16][8][72] f32.
__global__ __launch_bounds__(384) void k_mix(const float* __restrict__ data,
                                             const u16* __restrict__ ker,
                                             const u16* __restrict__ kccB,
                                             float* __restrict__ out, int b0) {
    int xt = blockIdx.x, rt = blockIdx.y, bi = blockIdx.z;
    int b = b0 + bi;
    int w0 = xt * 64, oy0 = rt * 6;
    int tid = threadIdx.x, wv = tid >> 6, lane = tid & 63;
    int l31 = lane & 31, lhi = lane >> 5;

    __shared__ __align__(16) float ldsD[16 * 8 * 72];   // 36 KiB

    const float* dbase = data + (size_t)b * CINC * HWSZ;
    const u16*   kbase = ker + (size_t)bi * HWPSZ * GCC;
    const u16*   kcb   = kccB + (size_t)b * COUTC * CINC;

    f32x16 acc[2][2] = {};    // [nj(o-half)][s(px-half)]

    for (int ck = 0; ck < 4; ++ck) {
        __syncthreads();
        // ---- stage data chunk: c in [ck*16,+16), rows oy0-1..oy0+6, iv w0-1..w0+64
        const float* dchunk = dbase + (size_t)ck * 16 * HWSZ;
        for (int it = tid; it < 2048; it += 384) {
            int q = it & 15;             // interior quad: iv = w0+4q..+3 -> dv 1+4q..
            int rc = it >> 4;            // cc*8 + drow
            int drow = rc & 7, cc = rc >> 3;
            int iu = oy0 - 1 + drow;
            float4 v = {0.f, 0.f, 0.f, 0.f};
            if (iu >= 0 && iu < HH)
                v = *(const float4*)(dchunk + (size_t)cc * HWSZ + (size_t)iu * WW + (w0 + 4 * q));
            float* dst = ldsD + cc * 576 + drow * 72 + 1 + 4 * q;
            dst[0] = v.x; dst[1] = v.y; dst[2] = v.z; dst[3] = v.w;
        }
        for (int it = tid; it < 256; it += 384) {        // edge cols dv=0,65
            int e = it & 1, rc = it >> 1;
            int drow = rc & 7, cc = rc >> 3;
            int iu = oy0 - 1 + drow;
            int dv = e ? 65 : 0;
            int iv = w0 - 1 + dv;
            float v = 0.f;
            if (iu >= 0 && iu < HH && iv >= 0 && iv < WW)
                v = dchunk[(size_t)cc * HWSZ + (size_t)iu * WW + iv];
            ldsD[cc * 576 + drow * 72 + dv] = v;
        }
        __syncthreads();

        // kcc A-frags for this K-chunk
        short8v ka0 = *(const short8v*)(kcb + ((size_t)(l31) * 64 + ck * 16 + lhi * 8));
        short8v ka1 = *(const short8v*)(kcb + ((size_t)(32 + l31) * 64 + ck * 16 + lhi * 8));

        #pragma unroll
        for (int s = 0; s < 2; ++s) {
            int vcol = s * 32 + l31;
            float x1v[8];
            #pragma unroll
            for (int j = 0; j < 8; ++j) x1v[j] = 0.f;
            #pragma unroll
            for (int di = 0; di < 3; ++di) {
                int u = oy0 + wv + di; if (u > 321) u = 321;   // clamp (unused waves)
                const u16* kr = kbase + ((size_t)u * WP + (w0 + vcol)) * GCC + ck * 16 + lhi * 8;
                const float* dp = ldsD + (lhi * 8) * 576 + (wv + di) * 72 + vcol;
                #pragma unroll
                for (int dj = 0; dj < 3; ++dj) {
                    u32x4 kv = *(const u32x4*)(kr + dj * 64);
                    const unsigned* kw = (const unsigned*)&kv;
                    #pragma unroll
                    for (int p = 0; p < 4; ++p) {
                        float klo = __uint_as_float(kw[p] << 16);
                        float khi = __uint_as_float(kw[p] & 0xffff0000u);
                        float dlo = dp[(2 * p) * 576 + dj];
                        float dhi = dp[(2 * p + 1) * 576 + dj];
                        x1v[2 * p]     += klo * dlo;
                        x1v[2 * p + 1] += khi * dhi;
                    }
                }
            }
            union { u16 h[8]; short8v v8; } xb;
            #pragma unroll
            for (int j = 0; j < 8; ++j) xb.h[j] = f2bf(x1v[j]);
            acc[0][s] = __builtin_amdgcn_mfma_f32_32x32x16_bf16(ka0, xb.v8, acc[0][s], 0, 0, 0);
            acc[1][s] = __builtin_amdgcn_mfma_f32_32x32x16_bf16(ka1, xb.v8, acc[1][s], 0, 0, 0);
        }
    }

    int oy = oy0 + wv;
    if (oy < HH) {
        #pragma unroll
        for (int nj = 0; nj < 2; ++nj)
            #pragma unroll
            for (int s = 0; s < 2; ++s)
                #pragma unroll
                for (int r = 0; r < 16; ++r) {
                    int o = nj * 32 + (r & 3) + 8 * (r >> 2) + 4 * lhi;
                    float v = acc[nj][s][r];
                    v = v > 0.f ? v : LEAK * v;
                    out[((size_t)(b * COUTC + o)) * HWSZ + (size_t)oy * WW + w0 + s * 32 + l31] = v;
                }
    }
}

// ---------------- K7: batchnorm stats ----------------
__global__ __launch_bounds__(256) void k_stats(const float* __restrict__ x,
                                               float* __restrict__ sums,
                                               float* __restrict__ sumsq) {
    int row = blockIdx.x;
    int o = row & 63;
    const float4* p = (const float4*)(x + (size_t)row * HWSZ);
    float s = 0.f, q = 0.f;
    for (int i = threadIdx.x; i < HWSZ / 4; i += 256) {
        float4 v = p[i];
        s += v.x + v.y + v.z + v.w;
        q += v.x * v.x + v.y * v.y + v.z * v.z + v.w * v.w;
    }
    #pragma unroll
    for (int off = 32; off; off >>= 1) { s += __shfl_down(s, off); q += __shfl_down(q, off); }
    __shared__ float ls[8];
    if ((threadIdx.x & 63) == 0) { ls[(threadIdx.x >> 6) * 2] = s; ls[(threadIdx.x >> 6) * 2 + 1] = q; }
    __syncthreads();
    if (threadIdx.x == 0) {
        s = ls[0] + ls[2] + ls[4] + ls[6];
        q = ls[1] + ls[3] + ls[5] + ls[7];
        atomicAdd(&sums[o], s);
        atomicAdd(&sumsq[o], q);
    }
}

__global__ void k_fin(const float* __restrict__ sums, const float* __restrict__ sumsq,
                      const float* __restrict__ gamma, const float* __restrict__ beta,
                      float* __restrict__ scale, float* __restrict__ shift) {
    int o = threadIdx.x;
    float n = (float)BB * (float)HWSZ;
    float mu = sums[o] / n;
    float var = sumsq[o] / n - mu * mu;
    float rs = rsqrtf(var + EPSB);
    float sc = rs * gamma[o];
    scale[o] = sc;
    shift[o] = beta[o] - mu * sc;
}

__global__ __launch_bounds__(256) void k_norm(float* __restrict__ x,
                                              const float* __restrict__ scale,
                                              const float* __restrict__ shift) {
    size_t i = (size_t)blockIdx.x * 256 + threadIdx.x;
    int ch = (int)((i * 4) / HWSZ) & 63;
    float4 v = ((float4*)x)[i];
    float sc = scale[ch], sh = shift[ch];
    v.x = v.x * sc + sh; v.y = v.y * sc + sh; v.z = v.z * sc + sh; v.w = v.w * sc + sh;
    ((float4*)x)[i] = v;
}

extern "C" void kernel_launch(void* const* d_in, const int* in_sizes, int n_in,
                              void* d_out, int out_size, void* d_ws, size_t ws_size,
                              hipStream_t stream) {
    const float* data  = (const float*)d_in[0];
    const float* guid  = (const float*)d_in[1];
    const float* w_kgl = (const float*)d_in[2];
    const float* b_kgl = (const float*)d_in[3];
    const float* w_cc  = (const float*)d_in[4];
    const float* b_cc  = (const float*)d_in[5];
    const float* gamma = (const float*)d_in[6];
    const float* beta  = (const float*)d_in[7];
    float* out = (float*)d_out;
    float* ws  = (float*)d_ws;

    // ws: [mean_g 512 f][sums 64][sumsq 64][scale 64][shift 64]  = 768 f32
    //     [kccB 32768 u16][wB 36864 u16][guidT bs*HWSZ*64 u16][ker bs*HWPSZ*64 u16]
    float* mean_g = ws;
    float* sums   = ws + 512;
    float* sumsq  = sums + 64;
    float* scale  = sumsq + 64;
    float* shift  = scale + 64;
    u16*   kccB   = (u16*)(ws + 768);
    u16*   wB     = kccB + BB * 4096;
    u16*   guidT  = wB + 9 * 4096;

    size_t used_us = 768 * 2 + BB * 4096 + 9 * 4096;
    size_t cap_us  = (ws_size / 2 > used_us) ? ws_size / 2 - used_us : 0;
    size_t per_b   = (size_t)HWSZ * GCC + (size_t)HWPSZ * GCC;
    int bs = 8;
    while (bs > 1 && (size_t)bs * per_b > cap_us) bs >>= 1;
    u16* kerb = guidT + (size_t)bs * HWSZ * GCC;

    k_mean<<<BB * GCC, 256, 0, stream>>>(guid, mean_g);
    k_kcc<<<(BB * COUTC * CINC + 255) / 256, 256, 0, stream>>>(mean_g, w_cc, b_cc, kccB);
    k_wb<<<(9 * 4096 + 255) / 256, 256, 0, stream>>>(w_kgl, wB);
    hipMemsetAsync(sums, 0, 2 * 64 * sizeof(float), stream);

    for (int b0 = 0; b0 < BB; b0 += bs) {
        int nb = (BB - b0 < bs) ? BB - b0 : bs;
        k_tr<<<dim3(WW / 64, HH, nb), 256, 0, stream>>>(guid, guidT, b0);
        k_convm<<<dim3(6, 54, nb), 384, 0, stream>>>(guidT, wB, b_kgl, kerb);
        k_mix<<<dim3(5, 54, nb), 384, 0, stream>>>(data, kerb, kccB, out, b0);
    }
    k_stats<<<BB * COUTC, 256, 0, stream>>>(out, sums, sumsq);
    k_fin<<<1, 64, 0, stream>>>(sums, sumsq, gamma, beta, scale, shift);
    k_norm<<<(out_size / 4 + 255) / 256, 256, 0, stream>>>(out, scale, shift);
}

// Round 5
// 739.898 us; speedup vs baseline: 4.7022x; 1.0713x over previous
//
#include <hip/hip_runtime.h>

#define BB 8
#define CINC 64
#define COUTC 64
#define GCC 64
#define HH 320
#define WW 320
#define HP 322
#define WP 322
#define LEAK 0.2f
#define EPSB 1e-5f
#define HWSZ (HH*WW)
#define HWPSZ (HP*WP)

typedef unsigned short u16;
typedef __attribute__((ext_vector_type(8))) short short8v;   // 8 bf16
typedef __attribute__((ext_vector_type(16))) float f32x16;   // MFMA 32x32 acc
typedef __attribute__((ext_vector_type(4))) unsigned int u32x4;

static __device__ __forceinline__ u16 f2bf(float f) {
    unsigned u = __float_as_uint(f);
    u += 0x7fffu + ((u >> 16) & 1u);      // RNE
    return (u16)(u >> 16);
}

// ---------------- K1: per-(b,g) mean of guidance ----------------
__global__ __launch_bounds__(256) void k_mean(const float* __restrict__ g,
                                              float* __restrict__ mean_g) {
    int row = blockIdx.x;
    const float4* p = (const float4*)(g + (size_t)row * HWSZ);
    float s = 0.f;
    for (int i = threadIdx.x; i < HWSZ / 4; i += 256) {
        float4 v = p[i];
        s += v.x + v.y + v.z + v.w;
    }
    #pragma unroll
    for (int off = 32; off; off >>= 1) s += __shfl_down(s, off);
    __shared__ float ls[4];
    if ((threadIdx.x & 63) == 0) ls[threadIdx.x >> 6] = s;
    __syncthreads();
    if (threadIdx.x == 0)
        mean_g[row] = (ls[0] + ls[1] + ls[2] + ls[3]) * (1.f / (float)HWSZ);
}

// ---------------- K2: kccB[b][o][c] bf16 ----------------
__global__ __launch_bounds__(256) void k_kcc(const float* __restrict__ mean_g,
                                             const float* __restrict__ w_cc,
                                             const float* __restrict__ b_cc,
                                             u16* __restrict__ kccB) {
    int idx = blockIdx.x * 256 + threadIdx.x;
    if (idx >= BB * COUTC * CINC) return;
    int b = idx >> 12;
    int j = idx & 4095;                  // o*64 + c
    const float* mg = mean_g + b * GCC;
    const float* wr = w_cc + (size_t)j * GCC;
    float s = b_cc[j];
    #pragma unroll
    for (int g = 0; g < GCC; ++g) s += mg[g] * wr[g];
    kccB[idx] = f2bf(s);
}

// ---------------- K3: wB[tap][cout][g] bf16 ----------------
__global__ __launch_bounds__(256) void k_wb(const float* __restrict__ w_kgl,
                                            u16* __restrict__ wB) {
    int i = blockIdx.x * 256 + threadIdx.x;      // tap*4096 + o*64 + g
    if (i >= 9 * 4096) return;
    int tap = i >> 12, o = (i >> 6) & 63, g = i & 63;
    wB[i] = f2bf(w_kgl[((size_t)(o * 64 + g)) * 9 + tap]);
}

// ---------------- K4: transpose guidance -> guidT bf16 [bi][h][w][g64] ----
__global__ __launch_bounds__(256) void k_tr(const float* __restrict__ guid,
                                            u16* __restrict__ guidT, int b0) {
    int w0 = blockIdx.x * 64;
    int h  = blockIdx.y;
    int bi = blockIdx.z;
    int bg = b0 + bi;
    int tid = threadIdx.x;
    __shared__ u16 tile[64][68];
    const float* src = guid + ((size_t)bg * GCC) * HWSZ + (size_t)h * WW + w0;
    #pragma unroll
    for (int k = 0; k < 4; ++k) {
        int i = tid + k * 256;               // g*16 + wq
        int g = i >> 4, wq = i & 15;
        float4 v = *(const float4*)(src + (size_t)g * HWSZ + wq * 4);
        tile[g][wq * 4 + 0] = f2bf(v.x);
        tile[g][wq * 4 + 1] = f2bf(v.y);
        tile[g][wq * 4 + 2] = f2bf(v.z);
        tile[g][wq * 4 + 3] = f2bf(v.w);
    }
    __syncthreads();
    u16* dst = guidT + (((size_t)bi * HH + h) * WW + w0) * GCC;
    #pragma unroll
    for (int k = 0; k < 2; ++k) {
        int i = tid + k * 256;               // w*8 + g8
        int w = i >> 3, g8 = i & 7;
        union { u16 s[8]; u32x4 v; } t;
        #pragma unroll
        for (int j = 0; j < 8; ++j) t.s[j] = tile[g8 * 8 + j][w];
        *(u32x4*)(dst + (size_t)w * GCC + g8 * 8) = t.v;
    }
}

// ---------------- K4b: data -> dataC bf16 chunk-major [bi][ck4][px][c16] --
__global__ __launch_bounds__(256) void k_trc(const float* __restrict__ data,
                                             u16* __restrict__ dataC, int b0) {
    int w0 = blockIdx.x * 64;
    int h  = blockIdx.y;
    int bi = blockIdx.z;
    int bg = b0 + bi;
    int tid = threadIdx.x;
    __shared__ u16 tile[64][68];
    const float* src = data + ((size_t)bg * CINC) * HWSZ + (size_t)h * WW + w0;
    #pragma unroll
    for (int k = 0; k < 4; ++k) {
        int i = tid + k * 256;               // c*16 + wq
        int c = i >> 4, wq = i & 15;
        float4 v = *(const float4*)(src + (size_t)c * HWSZ + wq * 4);
        tile[c][wq * 4 + 0] = f2bf(v.x);
        tile[c][wq * 4 + 1] = f2bf(v.y);
        tile[c][wq * 4 + 2] = f2bf(v.z);
        tile[c][wq * 4 + 3] = f2bf(v.w);
    }
    __syncthreads();
    u16* dst = dataC + (size_t)bi * HWSZ * CINC;
    #pragma unroll
    for (int k = 0; k < 2; ++k) {
        int i = tid + k * 256;               // w*8 + g8  (g8 = c-octet)
        int w = i >> 3, g8 = i & 7;
        union { u16 s[8]; u32x4 v; } t;
        #pragma unroll
        for (int j = 0; j < 8; ++j) t.s[j] = tile[g8 * 8 + j][w];
        size_t px = (size_t)h * WW + w0 + w;
        *(u32x4*)(dst + ((size_t)(g8 >> 1) * HWSZ + px) * 16 + (g8 & 1) * 8) = t.v;
    }
}

// ---------------- K5: MFMA conv -> kerC bf16 [bi][ck4][py*WP+px][c16] -----
__global__ __launch_bounds__(384) void k_convm(const u16* __restrict__ guidT,
                                               const u16* __restrict__ wB,
                                               const float* __restrict__ b_kgl,
                                               u16* __restrict__ ker) {
    int xt = blockIdx.x, rt = blockIdx.y, bi = blockIdx.z;
    int tid = threadIdx.x;
    int x0 = xt * 64, oy0 = rt * 6;
    __shared__ __align__(16) u16 lds[8 * 66 * 64];

    const u16* gsrc = guidT + (size_t)bi * HH * WW * GCC;
    for (int i = tid; i < 8 * 66 * 8; i += 384) {
        int rr = i / 528, rem = i - rr * 528;
        int cc = rem >> 3, u8 = rem & 7;
        int iy = oy0 - 2 + rr, ix = x0 - 2 + cc;
        u32x4 val = {0, 0, 0, 0};
        if (iy >= 0 && iy < HH && ix >= 0 && ix < WW)
            val = *(const u32x4*)(gsrc + ((size_t)iy * WW + ix) * GCC + u8 * 8);
        unsigned off = ((unsigned)(rr * 66 + cc) * 128u + (unsigned)u8 * 16u)
                       ^ ((unsigned)(cc & 7) << 4);
        *(u32x4*)((char*)lds + off) = val;
    }
    __syncthreads();

    int wv = tid >> 6, lane = tid & 63;
    int l31 = lane & 31, lhi = lane >> 5;
    f32x16 acc[2][2] = {};

    for (int tap = 0; tap < 9; ++tap) {
        int di = tap / 3, dj = tap - di * 3;
        short8v B[4][2];
        #pragma unroll
        for (int ks = 0; ks < 4; ++ks)
            #pragma unroll
            for (int nj = 0; nj < 2; ++nj)
                B[ks][nj] = *(const short8v*)(wB +
                    ((size_t)(tap * 64 + nj * 32 + l31) * 64 + ks * 16 + lhi * 8));
        int rrow = wv + di;
        #pragma unroll
        for (int ks = 0; ks < 4; ++ks)
            #pragma unroll
            for (int s = 0; s < 2; ++s) {
                int cc = s * 32 + l31 + dj;
                unsigned off = ((unsigned)(rrow * 66 + cc) * 128u +
                                (unsigned)(ks * 32 + lhi * 16))
                               ^ ((unsigned)(cc & 7) << 4);
                short8v a = *(const short8v*)((const char*)lds + off);
                acc[s][0] = __builtin_amdgcn_mfma_f32_32x32x16_bf16(a, B[ks][0], acc[s][0], 0, 0, 0);
                acc[s][1] = __builtin_amdgcn_mfma_f32_32x32x16_bf16(a, B[ks][1], acc[s][1], 0, 0, 0);
            }
    }

    int oy = oy0 + wv;
    if (oy < HP) {
        float bias0 = b_kgl[l31], bias1 = b_kgl[32 + l31];
        u16* kout = ker + (size_t)bi * HWPSZ * GCC;
        int ckl = l31 >> 4, idx = l31 & 15;
        #pragma unroll
        for (int s = 0; s < 2; ++s)
            #pragma unroll
            for (int r = 0; r < 16; ++r) {
                int pxc = x0 + s * 32 + (r & 3) + 8 * (r >> 2) + 4 * lhi;
                if (pxc < WP) {
                    size_t pix = (size_t)oy * WP + pxc;
                    kout[((size_t)ckl * HWPSZ + pix) * 16 + idx]       = f2bf(acc[s][0][r] + bias0);
                    kout[((size_t)(2 + ckl) * HWPSZ + pix) * 16 + idx] = f2bf(acc[s][1][r] + bias1);
                }
            }
    }
}

// ---------------- K6: k_mix v2 — shared prod + box-sum + MFMA mix ---------
// block 384 thr (6 waves), tile = 6 out rows x 64 px x 64 o, 4 c16 chunks.
// per chunk: prod[c2][8 rows][66 cols][8c] f32 in LDS (each elem loaded once,
// coalesced 16B), then x1 = 9-tap sum of prod (b128 reads), MFMA mix.
__global__ __launch_bounds__(384) void k_mix(const u16* __restrict__ dataC,
                                             const u16* __restrict__ ker,
                                             const u16* __restrict__ kccB,
                                             float* __restrict__ out, int b0) {
    int xt = blockIdx.x, rt = blockIdx.y, bi = blockIdx.z;
    int b = b0 + bi;
    int w0 = xt * 64, oy0 = rt * 6;
    int tid = threadIdx.x, wv = tid >> 6, lane = tid & 63;
    int l31 = lane & 31, lhi = lane >> 5;

    __shared__ __align__(16) float prd[2 * 528 * 8];   // 33792 B

    const u16* kerb = ker + (size_t)bi * HWPSZ * GCC;
    const u16* datb = dataC + (size_t)bi * HWSZ * CINC;
    const u16* kcb  = kccB + (size_t)b * COUTC * CINC;

    f32x16 acc[2][2] = {};    // [nj(o-half)][s(px-half)]

    for (int ck = 0; ck < 4; ++ck) {
        if (ck) __syncthreads();
        // ---- prod phase: 528 px x 2 c-octets, all loads coalesced, 1 touch
        #pragma unroll
        for (int t = tid; t < 1056; t += 384) {
            int c2 = t & 1, px = t >> 1;
            int r = px / 66, cc = px - r * 66;
            int u = oy0 + r, kcol = w0 + cc;
            int iu = u - 1, iv = kcol - 1;
            float pr[8];
            if (u < HP && iu >= 0 && iu < HH && iv >= 0 && iv < WW) {
                u32x4 kv = *(const u32x4*)(kerb + ((size_t)ck * HWPSZ + (size_t)u * WP + kcol) * 16 + c2 * 8);
                u32x4 dv = *(const u32x4*)(datb + ((size_t)ck * HWSZ + (size_t)iu * WW + iv) * 16 + c2 * 8);
                const unsigned* kw = (const unsigned*)&kv;
                const unsigned* dw = (const unsigned*)&dv;
                #pragma unroll
                for (int p = 0; p < 4; ++p) {
                    pr[2 * p]     = __uint_as_float(kw[p] << 16) * __uint_as_float(dw[p] << 16);
                    pr[2 * p + 1] = __uint_as_float(kw[p] & 0xffff0000u) * __uint_as_float(dw[p] & 0xffff0000u);
                }
            } else {
                #pragma unroll
                for (int j = 0; j < 8; ++j) pr[j] = 0.f;
            }
            float* pp = prd + c2 * 4224 + px * 8;
            *(float4*)pp       = make_float4(pr[0], pr[1], pr[2], pr[3]);
            *(float4*)(pp + 4) = make_float4(pr[4], pr[5], pr[6], pr[7]);
        }
        __syncthreads();

        // kcc A-frags for this K-chunk
        short8v ka0 = *(const short8v*)(kcb + ((size_t)l31 * 64 + ck * 16 + lhi * 8));
        short8v ka1 = *(const short8v*)(kcb + ((size_t)(32 + l31) * 64 + ck * 16 + lhi * 8));

        #pragma unroll
        for (int s = 0; s < 2; ++s) {
            float x1v[8];
            #pragma unroll
            for (int j = 0; j < 8; ++j) x1v[j] = 0.f;
            #pragma unroll
            for (int di = 0; di < 3; ++di) {
                int row = wv + di;
                #pragma unroll
                for (int dj = 0; dj < 3; ++dj) {
                    int col = s * 32 + l31 + dj;
                    const float* pp = prd + lhi * 4224 + (row * 66 + col) * 8;
                    float4 a0 = *(const float4*)pp;
                    float4 a1 = *(const float4*)(pp + 4);
                    x1v[0] += a0.x; x1v[1] += a0.y; x1v[2] += a0.z; x1v[3] += a0.w;
                    x1v[4] += a1.x; x1v[5] += a1.y; x1v[6] += a1.z; x1v[7] += a1.w;
                }
            }
            union { u16 h[8]; short8v v8; } xb;
            #pragma unroll
            for (int j = 0; j < 8; ++j) xb.h[j] = f2bf(x1v[j]);
            acc[0][s] = __builtin_amdgcn_mfma_f32_32x32x16_bf16(ka0, xb.v8, acc[0][s], 0, 0, 0);
            acc[1][s] = __builtin_amdgcn_mfma_f32_32x32x16_bf16(ka1, xb.v8, acc[1][s], 0, 0, 0);
        }
    }

    int oy = oy0 + wv;
    if (oy < HH) {
        #pragma unroll
        for (int nj = 0; nj < 2; ++nj)
            #pragma unroll
            for (int s = 0; s < 2; ++s)
                #pragma unroll
                for (int r = 0; r < 16; ++r) {
                    int o = nj * 32 + (r & 3) + 8 * (r >> 2) + 4 * lhi;
                    float v = acc[nj][s][r];
                    v = v > 0.f ? v : LEAK * v;
                    out[((size_t)(b * COUTC + o)) * HWSZ + (size_t)oy * WW + w0 + s * 32 + l31] = v;
                }
    }
}

// ---------------- K7: batchnorm stats ----------------
__global__ __launch_bounds__(256) void k_stats(const float* __restrict__ x,
                                               float* __restrict__ sums,
                                               float* __restrict__ sumsq) {
    int row = blockIdx.x;
    int o = row & 63;
    const float4* p = (const float4*)(x + (size_t)row * HWSZ);
    float s = 0.f, q = 0.f;
    for (int i = threadIdx.x; i < HWSZ / 4; i += 256) {
        float4 v = p[i];
        s += v.x + v.y + v.z + v.w;
        q += v.x * v.x + v.y * v.y + v.z * v.z + v.w * v.w;
    }
    #pragma unroll
    for (int off = 32; off; off >>= 1) { s += __shfl_down(s, off); q += __shfl_down(q, off); }
    __shared__ float ls[8];
    if ((threadIdx.x & 63) == 0) { ls[(threadIdx.x >> 6) * 2] = s; ls[(threadIdx.x >> 6) * 2 + 1] = q; }
    __syncthreads();
    if (threadIdx.x == 0) {
        s = ls[0] + ls[2] + ls[4] + ls[6];
        q = ls[1] + ls[3] + ls[5] + ls[7];
        atomicAdd(&sums[o], s);
        atomicAdd(&sumsq[o], q);
    }
}

__global__ void k_fin(const float* __restrict__ sums, const float* __restrict__ sumsq,
                      const float* __restrict__ gamma, const float* __restrict__ beta,
                      float* __restrict__ scale, float* __restrict__ shift) {
    int o = threadIdx.x;
    float n = (float)BB * (float)HWSZ;
    float mu = sums[o] / n;
    float var = sumsq[o] / n - mu * mu;
    float rs = rsqrtf(var + EPSB);
    float sc = rs * gamma[o];
    scale[o] = sc;
    shift[o] = beta[o] - mu * sc;
}

__global__ __launch_bounds__(256) void k_norm(float* __restrict__ x,
                                              const float* __restrict__ scale,
                                              const float* __restrict__ shift) {
    size_t i = (size_t)blockIdx.x * 256 + threadIdx.x;
    int ch = (int)((i * 4) / HWSZ) & 63;
    float4 v = ((float4*)x)[i];
    float sc = scale[ch], sh = shift[ch];
    v.x = v.x * sc + sh; v.y = v.y * sc + sh; v.z = v.z * sc + sh; v.w = v.w * sc + sh;
    ((float4*)x)[i] = v;
}

extern "C" void kernel_launch(void* const* d_in, const int* in_sizes, int n_in,
                              void* d_out, int out_size, void* d_ws, size_t ws_size,
                              hipStream_t stream) {
    const float* data  = (const float*)d_in[0];
    const float* guid  = (const float*)d_in[1];
    const float* w_kgl = (const float*)d_in[2];
    const float* b_kgl = (const float*)d_in[3];
    const float* w_cc  = (const float*)d_in[4];
    const float* b_cc  = (const float*)d_in[5];
    const float* gamma = (const float*)d_in[6];
    const float* beta  = (const float*)d_in[7];
    float* out = (float*)d_out;
    float* ws  = (float*)d_ws;

    // ws: [mean_g 512 f][sums 64][sumsq 64][scale 64][shift 64]  = 768 f32
    //     [kccB 32768 u16][wB 36864 u16][guidT bs*HWSZ*64][dataC bs*HWSZ*64]
    //     [kerC bs*HWPSZ*64]  (all u16)
    float* mean_g = ws;
    float* sums   = ws + 512;
    float* sumsq  = sums + 64;
    float* scale  = sumsq + 64;
    float* shift  = scale + 64;
    u16*   kccB   = (u16*)(ws + 768);
    u16*   wB     = kccB + BB * 4096;
    u16*   guidT  = wB + 9 * 4096;

    size_t used_us = 768 * 2 + BB * 4096 + 9 * 4096;
    size_t cap_us  = (ws_size / 2 > used_us) ? ws_size / 2 - used_us : 0;
    size_t per_b   = (size_t)GCC * (2 * HWSZ + HWPSZ);
    int bs = 8;
    while (bs > 1 && (size_t)bs * per_b > cap_us) bs >>= 1;
    u16* dataC = guidT + (size_t)bs * HWSZ * GCC;
    u16* kerC  = dataC + (size_t)bs * HWSZ * GCC;

    k_mean<<<BB * GCC, 256, 0, stream>>>(guid, mean_g);
    k_kcc<<<(BB * COUTC * CINC + 255) / 256, 256, 0, stream>>>(mean_g, w_cc, b_cc, kccB);
    k_wb<<<(9 * 4096 + 255) / 256, 256, 0, stream>>>(w_kgl, wB);
    hipMemsetAsync(sums, 0, 2 * 64 * sizeof(float), stream);

    for (int b0 = 0; b0 < BB; b0 += bs) {
        int nb = (BB - b0 < bs) ? BB - b0 : bs;
        k_tr<<<dim3(WW / 64, HH, nb), 256, 0, stream>>>(guid, guidT, b0);
        k_trc<<<dim3(WW / 64, HH, nb), 256, 0, stream>>>(data, dataC, b0);
        k_convm<<<dim3(6, 54, nb), 384, 0, stream>>>(guidT, wB, b_kgl, kerC);
        k_mix<<<dim3(5, 54, nb), 384, 0, stream>>>(dataC, kerC, kccB, out, b0);
    }
    k_stats<<<BB * COUTC, 256, 0, stream>>>(out, sums, sumsq);
    k_fin<<<1, 64, 0, stream>>>(sums, sumsq, gamma, beta, scale, shift);
    k_norm<<<(out_size / 4 + 255) / 256, 256, 0, stream>>>(out, scale, shift);
}

// Round 6
// 722.486 us; speedup vs baseline: 4.8156x; 1.0241x over previous
//
#include <hip/hip_runtime.h>

#define BB 8
#define CINC 64
#define COUTC 64
#define GCC 64
#define HH 320
#define WW 320
#define HP 322
#define WP 322
#define LEAK 0.2f
#define EPSB 1e-5f
#define HWSZ (HH*WW)
#define HWPSZ (HP*WP)

typedef unsigned short u16;
typedef __attribute__((ext_vector_type(8))) short short8v;   // 8 bf16
typedef __attribute__((ext_vector_type(16))) float f32x16;   // MFMA 32x32 acc
typedef __attribute__((ext_vector_type(4))) unsigned int u32x4;

static __device__ __forceinline__ u16 f2bf(float f) {
    unsigned u = __float_as_uint(f);
    u += 0x7fffu + ((u >> 16) & 1u);      // RNE
    return (u16)(u >> 16);
}
// A-tile LDS swizzle: spreads bits[6:4] uniformly for both stage-write and
// frag-read patterns (see derivation: bit6=cc&1 from 64B pixel stride;
// XOR bit5 with cc>>1, bit4 with cc>>2 -> all 8 slot-groups uniform).
static __device__ __forceinline__ unsigned swzA(int cc) {
    return (unsigned)((((cc >> 1) & 1) << 5) | (((cc >> 2) & 1) << 4));
}

// ---------------- K1: per-(b,g) mean of guidance ----------------
__global__ __launch_bounds__(256) void k_mean(const float* __restrict__ g,
                                              float* __restrict__ mean_g) {
    int row = blockIdx.x;
    const float4* p = (const float4*)(g + (size_t)row * HWSZ);
    float s = 0.f;
    for (int i = threadIdx.x; i < HWSZ / 4; i += 256) {
        float4 v = p[i];
        s += v.x + v.y + v.z + v.w;
    }
    #pragma unroll
    for (int off = 32; off; off >>= 1) s += __shfl_down(s, off);
    __shared__ float ls[4];
    if ((threadIdx.x & 63) == 0) ls[threadIdx.x >> 6] = s;
    __syncthreads();
    if (threadIdx.x == 0)
        mean_g[row] = (ls[0] + ls[1] + ls[2] + ls[3]) * (1.f / (float)HWSZ);
}

// ---------------- K2: kccB[b][o][c] bf16 ----------------
__global__ __launch_bounds__(256) void k_kcc(const float* __restrict__ mean_g,
                                             const float* __restrict__ w_cc,
                                             const float* __restrict__ b_cc,
                                             u16* __restrict__ kccB) {
    int idx = blockIdx.x * 256 + threadIdx.x;
    if (idx >= BB * COUTC * CINC) return;
    int b = idx >> 12;
    int j = idx & 4095;                  // o*64 + c
    const float* mg = mean_g + b * GCC;
    const float* wr = w_cc + (size_t)j * GCC;
    float s = b_cc[j];
    #pragma unroll
    for (int g = 0; g < GCC; ++g) s += mg[g] * wr[g];
    kccB[idx] = f2bf(s);
}

// ---------------- K3: wB2 = LDS-image of weights ----------------
// layout: [gc2][tap9][ks2][nj2][l31 32][lhi2][j8] u16 (36864 total)
// element = bf16(w_kgl[cout = nj*32+l][g = gc*32+ks*16+lhi*8+j][tap])
__global__ __launch_bounds__(256) void k_wb(const float* __restrict__ w_kgl,
                                            u16* __restrict__ wB) {
    int idx = blockIdx.x * 256 + threadIdx.x;
    if (idx >= 36864) return;
    int j   = idx & 7;
    int lhi = (idx >> 3) & 1;
    int l   = (idx >> 4) & 31;
    int nj  = (idx >> 9) & 1;
    int ks  = (idx >> 10) & 1;
    int t   = idx >> 11;          // gc*9 + tap
    int tap = t % 9, gc = t / 9;
    int cout = nj * 32 + l;
    int g = gc * 32 + ks * 16 + lhi * 8 + j;
    wB[idx] = f2bf(w_kgl[((size_t)(cout * 64 + g)) * 9 + tap]);
}

// ---------------- K4: transpose guidance -> guidT bf16 [bi][h][w][g64] ----
__global__ __launch_bounds__(256) void k_tr(const float* __restrict__ guid,
                                            u16* __restrict__ guidT, int b0) {
    int w0 = blockIdx.x * 64;
    int h  = blockIdx.y;
    int bi = blockIdx.z;
    int bg = b0 + bi;
    int tid = threadIdx.x;
    __shared__ u16 tile[64][68];
    const float* src = guid + ((size_t)bg * GCC) * HWSZ + (size_t)h * WW + w0;
    #pragma unroll
    for (int k = 0; k < 4; ++k) {
        int i = tid + k * 256;               // g*16 + wq
        int g = i >> 4, wq = i & 15;
        float4 v = *(const float4*)(src + (size_t)g * HWSZ + wq * 4);
        tile[g][wq * 4 + 0] = f2bf(v.x);
        tile[g][wq * 4 + 1] = f2bf(v.y);
        tile[g][wq * 4 + 2] = f2bf(v.z);
        tile[g][wq * 4 + 3] = f2bf(v.w);
    }
    __syncthreads();
    u16* dst = guidT + (((size_t)bi * HH + h) * WW + w0) * GCC;
    #pragma unroll
    for (int k = 0; k < 2; ++k) {
        int i = tid + k * 256;               // w*8 + g8
        int w = i >> 3, g8 = i & 7;
        union { u16 s[8]; u32x4 v; } t;
        #pragma unroll
        for (int j = 0; j < 8; ++j) t.s[j] = tile[g8 * 8 + j][w];
        *(u32x4*)(dst + (size_t)w * GCC + g8 * 8) = t.v;
    }
}

// ---------------- K4b: data -> dataC bf16 chunk-major [bi][ck4][px][c16] --
__global__ __launch_bounds__(256) void k_trc(const float* __restrict__ data,
                                             u16* __restrict__ dataC, int b0) {
    int w0 = blockIdx.x * 64;
    int h  = blockIdx.y;
    int bi = blockIdx.z;
    int bg = b0 + bi;
    int tid = threadIdx.x;
    __shared__ u16 tile[64][68];
    const float* src = data + ((size_t)bg * CINC) * HWSZ + (size_t)h * WW + w0;
    #pragma unroll
    for (int k = 0; k < 4; ++k) {
        int i = tid + k * 256;               // c*16 + wq
        int c = i >> 4, wq = i & 15;
        float4 v = *(const float4*)(src + (size_t)c * HWSZ + wq * 4);
        tile[c][wq * 4 + 0] = f2bf(v.x);
        tile[c][wq * 4 + 1] = f2bf(v.y);
        tile[c][wq * 4 + 2] = f2bf(v.z);
        tile[c][wq * 4 + 3] = f2bf(v.w);
    }
    __syncthreads();
    u16* dst = dataC + (size_t)bi * HWSZ * CINC;
    #pragma unroll
    for (int k = 0; k < 2; ++k) {
        int i = tid + k * 256;               // w*8 + g8  (g8 = c-octet)
        int w = i >> 3, g8 = i & 7;
        union { u16 s[8]; u32x4 v; } t;
        #pragma unroll
        for (int j = 0; j < 8; ++j) t.s[j] = tile[g8 * 8 + j][w];
        size_t px = (size_t)h * WW + w0 + w;
        *(u32x4*)(dst + ((size_t)(g8 >> 1) * HWSZ + px) * 16 + (g8 & 1) * 8) = t.v;
    }
}

// ---------------- K5: MFMA conv v2 -> kerC bf16 [bi][ck4][py*WP+px][c16] --
// 6 waves, tile 6 rows x 64 px x 64 couts. Two g-chunk phases (32 g each):
// B staged in LDS (linear copy of pre-transposed wB2), A staged swizzled.
// No global loads inside the tap loop.
__global__ __launch_bounds__(384) void k_convm(const u16* __restrict__ guidT,
                                               const u16* __restrict__ wB,
                                               const float* __restrict__ b_kgl,
                                               u16* __restrict__ ker) {
    int xt = blockIdx.x, rt = blockIdx.y, bi = blockIdx.z;
    int tid = threadIdx.x;
    int x0 = xt * 64, oy0 = rt * 6;
    __shared__ __align__(16) u16 ldsA[8 * 66 * 32];        // 33792 B
    __shared__ __align__(16) u16 ldsB[9 * 2 * 2 * 32 * 16]; // 36864 B

    int wv = tid >> 6, lane = tid & 63;
    int l31 = lane & 31, lhi = lane >> 5;
    f32x16 acc[2][2] = {};    // [s(px-half)][nj(cout-half)]

    const u16* gsrc = guidT + (size_t)bi * HH * WW * GCC;

    for (int gc = 0; gc < 2; ++gc) {
        if (gc) __syncthreads();
        // ---- stage B: linear 36864 B copy
        const u16* bsrc = wB + gc * 18432;
        #pragma unroll
        for (int k = 0; k < 6; ++k) {
            int i = tid + k * 384;
            *(u32x4*)(ldsB + (size_t)i * 8) = *(const u32x4*)(bsrc + (size_t)i * 8);
        }
        // ---- stage A: 8 rows x 66 cols x 4 g-octets (this 32-g chunk)
        for (int i = tid; i < 2112; i += 384) {
            int go = i & 3;
            int pc = i >> 2;
            int rr = pc / 66, cc = pc - rr * 66;
            int iy = oy0 - 2 + rr, ix = x0 - 2 + cc;
            u32x4 val = {0, 0, 0, 0};
            if (iy >= 0 && iy < HH && ix >= 0 && ix < WW)
                val = *(const u32x4*)(gsrc + ((size_t)iy * WW + ix) * GCC + gc * 32 + go * 8);
            unsigned off = ((unsigned)(pc * 4 + go) * 16u) ^ swzA(cc);
            *(u32x4*)((char*)ldsA + off) = val;
        }
        __syncthreads();

        // ---- compute: 9 taps x 2 ks x 2 s x 2 nj
        for (int tap = 0; tap < 9; ++tap) {
            int di = tap / 3, dj = tap - di * 3;
            short8v Bf[2][2];
            #pragma unroll
            for (int ks = 0; ks < 2; ++ks)
                #pragma unroll
                for (int nj = 0; nj < 2; ++nj)
                    Bf[ks][nj] = *(const short8v*)(ldsB +
                        ((((size_t)tap * 2 + ks) * 2 + nj) * 32 + l31) * 16 + lhi * 8);
            int rrow = wv + di;
            #pragma unroll
            for (int ks = 0; ks < 2; ++ks)
                #pragma unroll
                for (int s = 0; s < 2; ++s) {
                    int cc = s * 32 + l31 + dj;
                    unsigned off = ((unsigned)((rrow * 66 + cc) * 4 + ks * 2 + lhi) * 16u)
                                   ^ swzA(cc);
                    short8v a = *(const short8v*)((const char*)ldsA + off);
                    acc[s][0] = __builtin_amdgcn_mfma_f32_32x32x16_bf16(a, Bf[ks][0], acc[s][0], 0, 0, 0);
                    acc[s][1] = __builtin_amdgcn_mfma_f32_32x32x16_bf16(a, Bf[ks][1], acc[s][1], 0, 0, 0);
                }
        }
    }

    int oy = oy0 + wv;
    if (oy < HP) {
        float bias0 = b_kgl[l31], bias1 = b_kgl[32 + l31];
        u16* kout = ker + (size_t)bi * HWPSZ * GCC;
        int ckl = l31 >> 4, idx = l31 & 15;
        #pragma unroll
        for (int s = 0; s < 2; ++s)
            #pragma unroll
            for (int r = 0; r < 16; ++r) {
                int pxc = x0 + s * 32 + (r & 3) + 8 * (r >> 2) + 4 * lhi;
                if (pxc < WP) {
                    size_t pix = (size_t)oy * WP + pxc;
                    kout[((size_t)ckl * HWPSZ + pix) * 16 + idx]       = f2bf(acc[s][0][r] + bias0);
                    kout[((size_t)(2 + ckl) * HWPSZ + pix) * 16 + idx] = f2bf(acc[s][1][r] + bias1);
                }
            }
    }
}

// ---------------- K6: k_mix — shared prod + box-sum + MFMA mix + BN stats -
__global__ __launch_bounds__(384) void k_mix(const u16* __restrict__ dataC,
                                             const u16* __restrict__ ker,
                                             const u16* __restrict__ kccB,
                                             float* __restrict__ out,
                                             float* __restrict__ sums,
                                             float* __restrict__ sumsq, int b0) {
    int xt = blockIdx.x, rt = blockIdx.y, bi = blockIdx.z;
    int b = b0 + bi;
    int w0 = xt * 64, oy0 = rt * 6;
    int tid = threadIdx.x, wv = tid >> 6, lane = tid & 63;
    int l31 = lane & 31, lhi = lane >> 5;

    __shared__ __align__(16) float prd[2 * 528 * 8];   // 33792 B
    __shared__ float bsum[64], bsq[64];

    if (tid < 64) { bsum[tid] = 0.f; bsq[tid] = 0.f; }

    const u16* kerb = ker + (size_t)bi * HWPSZ * GCC;
    const u16* datb = dataC + (size_t)bi * HWSZ * CINC;
    const u16* kcb  = kccB + (size_t)b * COUTC * CINC;

    f32x16 acc[2][2] = {};    // [nj(o-half)][s(px-half)]

    for (int ck = 0; ck < 4; ++ck) {
        if (ck) __syncthreads();
        #pragma unroll
        for (int t = tid; t < 1056; t += 384) {
            int c2 = t & 1, px = t >> 1;
            int r = px / 66, cc = px - r * 66;
            int u = oy0 + r, kcol = w0 + cc;
            int iu = u - 1, iv = kcol - 1;
            float pr[8];
            if (u < HP && iu >= 0 && iu < HH && iv >= 0 && iv < WW) {
                u32x4 kv = *(const u32x4*)(kerb + ((size_t)ck * HWPSZ + (size_t)u * WP + kcol) * 16 + c2 * 8);
                u32x4 dv = *(const u32x4*)(datb + ((size_t)ck * HWSZ + (size_t)iu * WW + iv) * 16 + c2 * 8);
                const unsigned* kw = (const unsigned*)&kv;
                const unsigned* dw = (const unsigned*)&dv;
                #pragma unroll
                for (int p = 0; p < 4; ++p) {
                    pr[2 * p]     = __uint_as_float(kw[p] << 16) * __uint_as_float(dw[p] << 16);
                    pr[2 * p + 1] = __uint_as_float(kw[p] & 0xffff0000u) * __uint_as_float(dw[p] & 0xffff0000u);
                }
            } else {
                #pragma unroll
                for (int j = 0; j < 8; ++j) pr[j] = 0.f;
            }
            float* pp = prd + c2 * 4224 + px * 8;
            *(float4*)pp       = make_float4(pr[0], pr[1], pr[2], pr[3]);
            *(float4*)(pp + 4) = make_float4(pr[4], pr[5], pr[6], pr[7]);
        }
        __syncthreads();

        short8v ka0 = *(const short8v*)(kcb + ((size_t)l31 * 64 + ck * 16 + lhi * 8));
        short8v ka1 = *(const short8v*)(kcb + ((size_t)(32 + l31) * 64 + ck * 16 + lhi * 8));

        #pragma unroll
        for (int s = 0; s < 2; ++s) {
            float x1v[8];
            #pragma unroll
            for (int j = 0; j < 8; ++j) x1v[j] = 0.f;
            #pragma unroll
            for (int di = 0; di < 3; ++di) {
                int row = wv + di;
                #pragma unroll
                for (int dj = 0; dj < 3; ++dj) {
                    int col = s * 32 + l31 + dj;
                    const float* pp = prd + lhi * 4224 + (row * 66 + col) * 8;
                    float4 a0 = *(const float4*)pp;
                    float4 a1 = *(const float4*)(pp + 4);
                    x1v[0] += a0.x; x1v[1] += a0.y; x1v[2] += a0.z; x1v[3] += a0.w;
                    x1v[4] += a1.x; x1v[5] += a1.y; x1v[6] += a1.z; x1v[7] += a1.w;
                }
            }
            union { u16 h[8]; short8v v8; } xb;
            #pragma unroll
            for (int j = 0; j < 8; ++j) xb.h[j] = f2bf(x1v[j]);
            acc[0][s] = __builtin_amdgcn_mfma_f32_32x32x16_bf16(ka0, xb.v8, acc[0][s], 0, 0, 0);
            acc[1][s] = __builtin_amdgcn_mfma_f32_32x32x16_bf16(ka1, xb.v8, acc[1][s], 0, 0, 0);
        }
    }

    int oy = oy0 + wv;
    if (oy < HH) {
        #pragma unroll
        for (int nj = 0; nj < 2; ++nj)
            #pragma unroll
            for (int r = 0; r < 16; ++r) {
                int o = nj * 32 + (r & 3) + 8 * (r >> 2) + 4 * lhi;
                float v0 = acc[nj][0][r]; v0 = v0 > 0.f ? v0 : LEAK * v0;
                float v1 = acc[nj][1][r]; v1 = v1 > 0.f ? v1 : LEAK * v1;
                size_t rowb = ((size_t)(b * COUTC + o)) * HWSZ + (size_t)oy * WW + w0;
                out[rowb + l31]      = v0;
                out[rowb + 32 + l31] = v1;
                float ss = v0 + v1, qq = v0 * v0 + v1 * v1;
                #pragma unroll
                for (int off = 16; off; off >>= 1) {
                    ss += __shfl_xor(ss, off);
                    qq += __shfl_xor(qq, off);
                }
                if (l31 == 0) { atomicAdd(&bsum[o], ss); atomicAdd(&bsq[o], qq); }
            }
    }
    __syncthreads();
    if (tid < 64) {
        atomicAdd(&sums[tid], bsum[tid]);
        atomicAdd(&sumsq[tid], bsq[tid]);
    }
}

__global__ void k_fin(const float* __restrict__ sums, const float* __restrict__ sumsq,
                      const float* __restrict__ gamma, const float* __restrict__ beta,
                      float* __restrict__ scale, float* __restrict__ shift) {
    int o = threadIdx.x;
    float n = (float)BB * (float)HWSZ;
    float mu = sums[o] / n;
    float var = sumsq[o] / n - mu * mu;
    float rs = rsqrtf(var + EPSB);
    float sc = rs * gamma[o];
    scale[o] = sc;
    shift[o] = beta[o] - mu * sc;
}

__global__ __launch_bounds__(256) void k_norm(float* __restrict__ x,
                                              const float* __restrict__ scale,
                                              const float* __restrict__ shift) {
    size_t i = (size_t)blockIdx.x * 256 + threadIdx.x;
    int ch = (int)((i * 4) / HWSZ) & 63;
    float4 v = ((float4*)x)[i];
    float sc = scale[ch], sh = shift[ch];
    v.x = v.x * sc + sh; v.y = v.y * sc + sh; v.z = v.z * sc + sh; v.w = v.w * sc + sh;
    ((float4*)x)[i] = v;
}

extern "C" void kernel_launch(void* const* d_in, const int* in_sizes, int n_in,
                              void* d_out, int out_size, void* d_ws, size_t ws_size,
                              hipStream_t stream) {
    const float* data  = (const float*)d_in[0];
    const float* guid  = (const float*)d_in[1];
    const float* w_kgl = (const float*)d_in[2];
    const float* b_kgl = (const float*)d_in[3];
    const float* w_cc  = (const float*)d_in[4];
    const float* b_cc  = (const float*)d_in[5];
    const float* gamma = (const float*)d_in[6];
    const float* beta  = (const float*)d_in[7];
    float* out = (float*)d_out;
    float* ws  = (float*)d_ws;

    // ws: [mean_g 512 f][sums 64][sumsq 64][scale 64][shift 64]  = 768 f32
    //     [kccB 32768 u16][wB2 36864 u16][guidT bs*HWSZ*64][dataC bs*HWSZ*64]
    //     [kerC bs*HWPSZ*64]  (all u16)
    float* mean_g = ws;
    float* sums   = ws + 512;
    float* sumsq  = sums + 64;
    float* scale  = sumsq + 64;
    float* shift  = scale + 64;
    u16*   kccB   = (u16*)(ws + 768);
    u16*   wB     = kccB + BB * 4096;
    u16*   guidT  = wB + 36864;

    size_t used_us = 768 * 2 + BB * 4096 + 36864;
    size_t cap_us  = (ws_size / 2 > used_us) ? ws_size / 2 - used_us : 0;
    size_t per_b   = (size_t)GCC * (2 * HWSZ + HWPSZ);
    // bs=2: per-chunk working set (guidT+dataC+kerC = 79 MB) stays L3-resident
    int bs = 2;
    while (bs > 1 && (size_t)bs * per_b > cap_us) bs >>= 1;
    u16* dataC = guidT + (size_t)bs * HWSZ * GCC;
    u16* kerC  = dataC + (size_t)bs * HWSZ * GCC;

    k_mean<<<BB * GCC, 256, 0, stream>>>(guid, mean_g);
    k_kcc<<<(BB * COUTC * CINC + 255) / 256, 256, 0, stream>>>(mean_g, w_cc, b_cc, kccB);
    k_wb<<<144, 256, 0, stream>>>(w_kgl, wB);
    hipMemsetAsync(sums, 0, 2 * 64 * sizeof(float), stream);

    for (int b0 = 0; b0 < BB; b0 += bs) {
        int nb = (BB - b0 < bs) ? BB - b0 : bs;
        k_tr<<<dim3(WW / 64, HH, nb), 256, 0, stream>>>(guid, guidT, b0);
        k_trc<<<dim3(WW / 64, HH, nb), 256, 0, stream>>>(data, dataC, b0);
        k_convm<<<dim3(6, 54, nb), 384, 0, stream>>>(guidT, wB, b_kgl, kerC);
        k_mix<<<dim3(5, 54, nb), 384, 0, stream>>>(dataC, kerC, kccB, out, sums, sumsq, b0);
    }
    k_fin<<<1, 64, 0, stream>>>(sums, sumsq, gamma, beta, scale, shift);
    k_norm<<<(out_size / 4 + 255) / 256, 256, 0, stream>>>(out, scale, shift);
}

// Round 7
// 710.271 us; speedup vs baseline: 4.8984x; 1.0172x over previous
//
#include <hip/hip_runtime.h>

#define BB 8
#define CINC 64
#define COUTC 64
#define GCC 64
#define HH 320
#define WW 320
#define HP 322
#define WP 322
#define LEAK 0.2f
#define EPSB 1e-5f
#define HWSZ (HH*WW)
#define HWPSZ (HP*WP)

typedef unsigned short u16;
typedef __attribute__((ext_vector_type(8))) short short8v;   // 8 bf16
typedef __attribute__((ext_vector_type(16))) float f32x16;   // MFMA 32x32 acc
typedef __attribute__((ext_vector_type(4))) unsigned int u32x4;

static __device__ __forceinline__ u16 f2bf(float f) {
    unsigned u = __float_as_uint(f);
    u += 0x7fffu + ((u >> 16) & 1u);      // RNE
    return (u16)(u >> 16);
}
static __device__ __forceinline__ float bf2f(u16 h) {
    return __uint_as_float((unsigned)h << 16);
}
// A-tile LDS swizzle (see R6 derivation)
static __device__ __forceinline__ unsigned swzA(int cc) {
    return (unsigned)((((cc >> 1) & 1) << 5) | (((cc >> 2) & 1) << 4));
}

// ---------------- K2: kccB[b][o][c] bf16 (means from atomic sums) ---------
__global__ __launch_bounds__(256) void k_kcc(const float* __restrict__ mean_sums,
                                             const float* __restrict__ w_cc,
                                             const float* __restrict__ b_cc,
                                             u16* __restrict__ kccB, int b0) {
    int li = blockIdx.x * 256 + threadIdx.x;
    int b = b0 + (li >> 12);
    int j = li & 4095;                   // o*64 + c
    const float* mg = mean_sums + b * GCC;
    const float* wr = w_cc + (size_t)j * GCC;
    float s = b_cc[j];
    #pragma unroll
    for (int g = 0; g < GCC; ++g) s += mg[g] * (1.f / (float)HWSZ) * wr[g];
    kccB[(size_t)b * 4096 + j] = f2bf(s);
}

// ---------------- K3: wB = LDS image [gc][ks][tap][nj][l31][lhi][j] -------
__global__ __launch_bounds__(256) void k_wb(const float* __restrict__ w_kgl,
                                            u16* __restrict__ wB) {
    int idx = blockIdx.x * 256 + threadIdx.x;
    if (idx >= 36864) return;
    int j   = idx & 7;
    int lhi = (idx >> 3) & 1;
    int l   = (idx >> 4) & 31;
    int nj  = (idx >> 9) & 1;
    int t   = idx >> 10;          // (gc*2+ks)*9 + tap
    int tap = t % 9, gk = t / 9;
    int ks = gk & 1, gc = gk >> 1;
    int cout = nj * 32 + l;
    int g = gc * 32 + ks * 16 + lhi * 8 + j;
    wB[idx] = f2bf(w_kgl[((size_t)(cout * 64 + g)) * 9 + tap]);
}

// ---------------- K4: merged transpose (guid->guidT, data->dataC) + mean --
// grid z: [0,nb) = guidance (+mean atomics), [nb,2nb) = data
__global__ __launch_bounds__(256) void k_trall(const float* __restrict__ guid,
                                               const float* __restrict__ data,
                                               u16* __restrict__ guidT,
                                               u16* __restrict__ dataC,
                                               float* __restrict__ mean_sums,
                                               int b0, int nb) {
    int w0 = blockIdx.x * 64;
    int h  = blockIdx.y;
    int zi = blockIdx.z;
    int isData = zi >= nb;
    int bi = isData ? zi - nb : zi;
    int bg = b0 + bi;
    int tid = threadIdx.x;
    __shared__ u16 tile[64][68];
    const float* src = (isData ? data : guid) + ((size_t)bg * 64) * HWSZ
                       + (size_t)h * WW + w0;
    #pragma unroll
    for (int k = 0; k < 4; ++k) {
        int i = tid + k * 256;               // c*16 + wq
        int c = i >> 4, wq = i & 15;
        float4 v = *(const float4*)(src + (size_t)c * HWSZ + wq * 4);
        tile[c][wq * 4 + 0] = f2bf(v.x);
        tile[c][wq * 4 + 1] = f2bf(v.y);
        tile[c][wq * 4 + 2] = f2bf(v.z);
        tile[c][wq * 4 + 3] = f2bf(v.w);
    }
    __syncthreads();
    if (isData) {
        u16* dst = dataC + (size_t)bi * HWSZ * CINC;
        #pragma unroll
        for (int k = 0; k < 2; ++k) {
            int i = tid + k * 256;           // w*8 + g8 (c-octet)
            int w = i >> 3, g8 = i & 7;
            union { u16 s[8]; u32x4 v; } t;
            #pragma unroll
            for (int j = 0; j < 8; ++j) t.s[j] = tile[g8 * 8 + j][w];
            size_t px = (size_t)h * WW + w0 + w;
            *(u32x4*)(dst + ((size_t)(g8 >> 1) * HWSZ + px) * 16 + (g8 & 1) * 8) = t.v;
        }
    } else {
        u16* dst = guidT + (((size_t)bi * HH + h) * WW + w0) * GCC;
        #pragma unroll
        for (int k = 0; k < 2; ++k) {
            int i = tid + k * 256;           // w*8 + g8
            int w = i >> 3, g8 = i & 7;
            union { u16 s[8]; u32x4 v; } t;
            #pragma unroll
            for (int j = 0; j < 8; ++j) t.s[j] = tile[g8 * 8 + j][w];
            *(u32x4*)(dst + (size_t)w * GCC + g8 * 8) = t.v;
        }
        if (tid < 64) {                      // per-g row sum for mean
            float s = 0.f;
            #pragma unroll
            for (int w = 0; w < 64; ++w) s += bf2f(tile[tid][w]);
            atomicAdd(&mean_sums[bg * GCC + tid], s);
        }
    }
}

// ---------------- K5: MFMA conv -> kerC bf16 [bi][ck4][py*WP+px][c16] -----
// 6 waves, tile 6 rows x 64 px x 64 couts. 4 phases (gc x ks): B staged
// per-ks (18432 B), A staged per-gc swizzled (33792 B). LDS 52224 -> 3/CU.
__global__ __launch_bounds__(384) void k_convm(const u16* __restrict__ guidT,
                                               const u16* __restrict__ wB,
                                               const float* __restrict__ b_kgl,
                                               u16* __restrict__ ker) {
    int xt = blockIdx.x, rt = blockIdx.y, bi = blockIdx.z;
    int tid = threadIdx.x;
    int x0 = xt * 64, oy0 = rt * 6;
    __shared__ __align__(16) u16 ldsA[8 * 66 * 32];        // 33792 B
    __shared__ __align__(16) u16 ldsB[9 * 2 * 32 * 16];    // 18432 B

    int wv = tid >> 6, lane = tid & 63;
    int l31 = lane & 31, lhi = lane >> 5;
    f32x16 acc[2][2] = {};    // [s(px-half)][nj(cout-half)]

    const u16* gsrc = guidT + (size_t)bi * HH * WW * GCC;

    for (int gc = 0; gc < 2; ++gc) {
        for (int ks = 0; ks < 2; ++ks) {
            if (gc | ks) __syncthreads();
            // ---- stage B: linear 18432 B copy
            const u16* bsrc = wB + (gc * 2 + ks) * 9216;
            #pragma unroll
            for (int k = 0; k < 3; ++k) {
                int i = tid + k * 384;
                *(u32x4*)(ldsB + (size_t)i * 8) = *(const u32x4*)(bsrc + (size_t)i * 8);
            }
            // ---- stage A (once per gc): 8 rows x 66 cols x 4 g-octets
            if (ks == 0)
                for (int i = tid; i < 2112; i += 384) {
                    int go = i & 3;
                    int pc = i >> 2;
                    int rr = pc / 66, cc = pc - rr * 66;
                    int iy = oy0 - 2 + rr, ix = x0 - 2 + cc;
                    u32x4 val = {0, 0, 0, 0};
                    if (iy >= 0 && iy < HH && ix >= 0 && ix < WW)
                        val = *(const u32x4*)(gsrc + ((size_t)iy * WW + ix) * GCC + gc * 32 + go * 8);
                    unsigned off = ((unsigned)(pc * 4 + go) * 16u) ^ swzA(cc);
                    *(u32x4*)((char*)ldsA + off) = val;
                }
            __syncthreads();

            // ---- compute: 9 taps x 2 s x 2 nj (36 MFMA)
            for (int tap = 0; tap < 9; ++tap) {
                int di = tap / 3, dj = tap - di * 3;
                short8v Bf[2];
                #pragma unroll
                for (int nj = 0; nj < 2; ++nj)
                    Bf[nj] = *(const short8v*)(ldsB +
                        (((size_t)tap * 2 + nj) * 32 + l31) * 16 + lhi * 8);
                int rrow = wv + di;
                #pragma unroll
                for (int s = 0; s < 2; ++s) {
                    int cc = s * 32 + l31 + dj;
                    unsigned off = ((unsigned)((rrow * 66 + cc) * 4 + ks * 2 + lhi) * 16u)
                                   ^ swzA(cc);
                    short8v a = *(const short8v*)((const char*)ldsA + off);
                    acc[s][0] = __builtin_amdgcn_mfma_f32_32x32x16_bf16(a, Bf[0], acc[s][0], 0, 0, 0);
                    acc[s][1] = __builtin_amdgcn_mfma_f32_32x32x16_bf16(a, Bf[1], acc[s][1], 0, 0, 0);
                }
            }
        }
    }

    int oy = oy0 + wv;
    if (oy < HP) {
        float bias0 = b_kgl[l31], bias1 = b_kgl[32 + l31];
        u16* kout = ker + (size_t)bi * HWPSZ * GCC;
        int ckl = l31 >> 4, idx = l31 & 15;
        #pragma unroll
        for (int s = 0; s < 2; ++s)
            #pragma unroll
            for (int r = 0; r < 16; ++r) {
                int pxc = x0 + s * 32 + (r & 3) + 8 * (r >> 2) + 4 * lhi;
                if (pxc < WP) {
                    size_t pix = (size_t)oy * WP + pxc;
                    kout[((size_t)ckl * HWPSZ + pix) * 16 + idx]       = f2bf(acc[s][0][r] + bias0);
                    kout[((size_t)(2 + ckl) * HWPSZ + pix) * 16 + idx] = f2bf(acc[s][1][r] + bias1);
                }
            }
    }
}

// ---------------- K6: k_mix — shared prod + box-sum + MFMA mix + BN stats -
__global__ __launch_bounds__(384) void k_mix(const u16* __restrict__ dataC,
                                             const u16* __restrict__ ker,
                                             const u16* __restrict__ kccB,
                                             float* __restrict__ out,
                                             float* __restrict__ stats, int b0) {
    int xt = blockIdx.x, rt = blockIdx.y, bi = blockIdx.z;
    int b = b0 + bi;
    int w0 = xt * 64, oy0 = rt * 6;
    int tid = threadIdx.x, wv = tid >> 6, lane = tid & 63;
    int l31 = lane & 31, lhi = lane >> 5;

    __shared__ __align__(16) float prd[2 * 528 * 8];   // 33792 B
    __shared__ float bsum[64], bsq[64];

    if (tid < 64) { bsum[tid] = 0.f; bsq[tid] = 0.f; }

    const u16* kerb = ker + (size_t)bi * HWPSZ * GCC;
    const u16* datb = dataC + (size_t)bi * HWSZ * CINC;
    const u16* kcb  = kccB + (size_t)b * COUTC * CINC;

    f32x16 acc[2][2] = {};    // [nj(o-half)][s(px-half)]

    for (int ck = 0; ck < 4; ++ck) {
        if (ck) __syncthreads();
        #pragma unroll
        for (int t = tid; t < 1056; t += 384) {
            int c2 = t & 1, px = t >> 1;
            int r = px / 66, cc = px - r * 66;
            int u = oy0 + r, kcol = w0 + cc;
            int iu = u - 1, iv = kcol - 1;
            float pr[8];
            if (u < HP && iu >= 0 && iu < HH && iv >= 0 && iv < WW) {
                u32x4 kv = *(const u32x4*)(kerb + ((size_t)ck * HWPSZ + (size_t)u * WP + kcol) * 16 + c2 * 8);
                u32x4 dv = *(const u32x4*)(datb + ((size_t)ck * HWSZ + (size_t)iu * WW + iv) * 16 + c2 * 8);
                const unsigned* kw = (const unsigned*)&kv;
                const unsigned* dw = (const unsigned*)&dv;
                #pragma unroll
                for (int p = 0; p < 4; ++p) {
                    pr[2 * p]     = __uint_as_float(kw[p] << 16) * __uint_as_float(dw[p] << 16);
                    pr[2 * p + 1] = __uint_as_float(kw[p] & 0xffff0000u) * __uint_as_float(dw[p] & 0xffff0000u);
                }
            } else {
                #pragma unroll
                for (int j = 0; j < 8; ++j) pr[j] = 0.f;
            }
            float* pp = prd + c2 * 4224 + px * 8;
            *(float4*)pp       = make_float4(pr[0], pr[1], pr[2], pr[3]);
            *(float4*)(pp + 4) = make_float4(pr[4], pr[5], pr[6], pr[7]);
        }
        __syncthreads();

        short8v ka0 = *(const short8v*)(kcb + ((size_t)l31 * 64 + ck * 16 + lhi * 8));
        short8v ka1 = *(const short8v*)(kcb + ((size_t)(32 + l31) * 64 + ck * 16 + lhi * 8));

        #pragma unroll
        for (int s = 0; s < 2; ++s) {
            float x1v[8];
            #pragma unroll
            for (int j = 0; j < 8; ++j) x1v[j] = 0.f;
            #pragma unroll
            for (int di = 0; di < 3; ++di) {
                int row = wv + di;
                #pragma unroll
                for (int dj = 0; dj < 3; ++dj) {
                    int col = s * 32 + l31 + dj;
                    const float* pp = prd + lhi * 4224 + (row * 66 + col) * 8;
                    float4 a0 = *(const float4*)pp;
                    float4 a1 = *(const float4*)(pp + 4);
                    x1v[0] += a0.x; x1v[1] += a0.y; x1v[2] += a0.z; x1v[3] += a0.w;
                    x1v[4] += a1.x; x1v[5] += a1.y; x1v[6] += a1.z; x1v[7] += a1.w;
                }
            }
            union { u16 h[8]; short8v v8; } xb;
            #pragma unroll
            for (int j = 0; j < 8; ++j) xb.h[j] = f2bf(x1v[j]);
            acc[0][s] = __builtin_amdgcn_mfma_f32_32x32x16_bf16(ka0, xb.v8, acc[0][s], 0, 0, 0);
            acc[1][s] = __builtin_amdgcn_mfma_f32_32x32x16_bf16(ka1, xb.v8, acc[1][s], 0, 0, 0);
        }
    }

    int oy = oy0 + wv;
    if (oy < HH) {
        #pragma unroll
        for (int nj = 0; nj < 2; ++nj)
            #pragma unroll
            for (int r = 0; r < 16; ++r) {
                int o = nj * 32 + (r & 3) + 8 * (r >> 2) + 4 * lhi;
                float v0 = acc[nj][0][r]; v0 = v0 > 0.f ? v0 : LEAK * v0;
                float v1 = acc[nj][1][r]; v1 = v1 > 0.f ? v1 : LEAK * v1;
                size_t rowb = ((size_t)(b * COUTC + o)) * HWSZ + (size_t)oy * WW + w0;
                out[rowb + l31]      = v0;
                out[rowb + 32 + l31] = v1;
                float ss = v0 + v1, qq = v0 * v0 + v1 * v1;
                #pragma unroll
                for (int off = 16; off; off >>= 1) {
                    ss += __shfl_xor(ss, off);
                    qq += __shfl_xor(qq, off);
                }
                if (l31 == 0) { atomicAdd(&bsum[o], ss); atomicAdd(&bsq[o], qq); }
            }
    }
    __syncthreads();
    // 8-way replicated accumulators: stats[rep][0][64]=sum, [rep][1][64]=sq
    int rep = (blockIdx.x + blockIdx.y * 5 + blockIdx.z * 3) & 7;
    if (tid < 64) {
        atomicAdd(&stats[rep * 128 + tid], bsum[tid]);
        atomicAdd(&stats[rep * 128 + 64 + tid], bsq[tid]);
    }
}

__global__ void k_fin(const float* __restrict__ stats,
                      const float* __restrict__ gamma, const float* __restrict__ beta,
                      float* __restrict__ scale, float* __restrict__ shift) {
    int o = threadIdx.x;
    float s = 0.f, q = 0.f;
    #pragma unroll
    for (int r = 0; r < 8; ++r) { s += stats[r * 128 + o]; q += stats[r * 128 + 64 + o]; }
    float n = (float)BB * (float)HWSZ;
    float mu = s / n;
    float var = q / n - mu * mu;
    float rs = rsqrtf(var + EPSB);
    float sc = rs * gamma[o];
    scale[o] = sc;
    shift[o] = beta[o] - mu * sc;
}

__global__ __launch_bounds__(256) void k_norm(float* __restrict__ x,
                                              const float* __restrict__ scale,
                                              const float* __restrict__ shift) {
    size_t i = (size_t)blockIdx.x * 256 + threadIdx.x;
    int ch = (int)((i * 4) / HWSZ) & 63;
    float4 v = ((float4*)x)[i];
    float sc = scale[ch], sh = shift[ch];
    v.x = v.x * sc + sh; v.y = v.y * sc + sh; v.z = v.z * sc + sh; v.w = v.w * sc + sh;
    ((float4*)x)[i] = v;
}

extern "C" void kernel_launch(void* const* d_in, const int* in_sizes, int n_in,
                              void* d_out, int out_size, void* d_ws, size_t ws_size,
                              hipStream_t stream) {
    const float* data  = (const float*)d_in[0];
    const float* guid  = (const float*)d_in[1];
    const float* w_kgl = (const float*)d_in[2];
    const float* b_kgl = (const float*)d_in[3];
    const float* w_cc  = (const float*)d_in[4];
    const float* b_cc  = (const float*)d_in[5];
    const float* gamma = (const float*)d_in[6];
    const float* beta  = (const float*)d_in[7];
    float* out = (float*)d_out;
    float* ws  = (float*)d_ws;

    // ws (f32): [mean_sums 512][stats 8*128][scale 64][shift 64] = 1664
    // then u16: [kccB 32768][wB 36864][guidT bs*HWSZ*64][dataC bs*HWSZ*64]
    //           [kerC bs*HWPSZ*64]
    float* mean_sums = ws;
    float* stats     = ws + 512;
    float* scale     = stats + 1024;
    float* shift     = scale + 64;
    u16*   kccB      = (u16*)(ws + 1664);
    u16*   wB        = kccB + BB * 4096;
    u16*   guidT     = wB + 36864;

    size_t used_us = 1664 * 2 + BB * 4096 + 36864;
    size_t cap_us  = (ws_size / 2 > used_us) ? ws_size / 2 - used_us : 0;
    size_t per_b   = (size_t)GCC * (2 * HWSZ + HWPSZ);
    // bs=4: chunk working set (guidT+dataC+kerC = 158 MB) is L3-resident
    int bs = 4;
    while (bs > 1 && (size_t)bs * per_b > cap_us) bs >>= 1;
    u16* dataC = guidT + (size_t)bs * HWSZ * GCC;
    u16* kerC  = dataC + (size_t)bs * HWSZ * GCC;

    hipMemsetAsync(ws, 0, 1536 * sizeof(float), stream);   // mean_sums + stats
    k_wb<<<144, 256, 0, stream>>>(w_kgl, wB);

    for (int b0 = 0; b0 < BB; b0 += bs) {
        int nb = (BB - b0 < bs) ? BB - b0 : bs;
        k_trall<<<dim3(WW / 64, HH, 2 * nb), 256, 0, stream>>>(guid, data, guidT, dataC,
                                                               mean_sums, b0, nb);
        k_kcc<<<nb * 16, 256, 0, stream>>>(mean_sums, w_cc, b_cc, kccB, b0);
        k_convm<<<dim3(6, 54, nb), 384, 0, stream>>>(guidT, wB, b_kgl, kerC);
        k_mix<<<dim3(5, 54, nb), 384, 0, stream>>>(dataC, kerC, kccB, out, stats, b0);
    }
    k_fin<<<1, 64, 0, stream>>>(stats, gamma, beta, scale, shift);
    k_norm<<<(out_size / 4 + 255) / 256, 256, 0, stream>>>(out, scale, shift);
}

// Round 10
// 645.273 us; speedup vs baseline: 5.3918x; 1.1007x over previous
//
#include <hip/hip_runtime.h>

#define BB 8
#define CINC 64
#define COUTC 64
#define GCC 64
#define HH 320
#define WW 320
#define HP 322
#define WP 322
#define LEAK 0.2f
#define EPSB 1e-5f
#define HWSZ (HH*WW)
#define HWPSZ (HP*WP)

typedef unsigned short u16;
typedef __attribute__((ext_vector_type(8))) short short8v;   // 8 bf16
typedef __attribute__((ext_vector_type(16))) float f32x16;   // MFMA 32x32 acc
typedef __attribute__((ext_vector_type(4))) unsigned int u32x4;

static __device__ __forceinline__ u16 f2bf(float f) {
    unsigned u = __float_as_uint(f);
    u += 0x7fffu + ((u >> 16) & 1u);      // RNE
    return (u16)(u >> 16);
}
static __device__ __forceinline__ unsigned pk2bf(float a, float b) {
    return (unsigned)f2bf(a) | ((unsigned)f2bf(b) << 16);
}
// A-tile LDS swizzle (R6/R7-verified key)
static __device__ __forceinline__ unsigned swzA(int cc) {
    return (unsigned)((((cc >> 1) & 1) << 5) | (((cc >> 2) & 1) << 4));
}

// ---------------- K1: per-(b,g) mean of guidance (R4-verified) ------------
__global__ __launch_bounds__(256) void k_mean(const float* __restrict__ g,
                                              float* __restrict__ mean_g) {
    int row = blockIdx.x;                       // b*GC + gc
    const float4* p = (const float4*)(g + (size_t)row * HWSZ);
    float s = 0.f;
    for (int i = threadIdx.x; i < HWSZ / 4; i += 256) {
        float4 v = p[i];
        s += v.x + v.y + v.z + v.w;
    }
    #pragma unroll
    for (int off = 32; off; off >>= 1) s += __shfl_down(s, off);
    __shared__ float ls[4];
    if ((threadIdx.x & 63) == 0) ls[threadIdx.x >> 6] = s;
    __syncthreads();
    if (threadIdx.x == 0)
        mean_g[row] = (ls[0] + ls[1] + ls[2] + ls[3]) * (1.f / (float)HWSZ);
}

// ---------------- K2: kccB[b][o][c] bf16 (R4-verified) --------------------
__global__ __launch_bounds__(256) void k_kcc(const float* __restrict__ mean_g,
                                             const float* __restrict__ w_cc,
                                             const float* __restrict__ b_cc,
                                             u16* __restrict__ kccB) {
    int idx = blockIdx.x * 256 + threadIdx.x;
    if (idx >= BB * COUTC * CINC) return;
    int b = idx >> 12;
    int j = idx & 4095;                  // o*64 + c
    const float* mg = mean_g + b * GCC;
    const float* wr = w_cc + (size_t)j * GCC;
    float s = b_cc[j];
    #pragma unroll
    for (int g = 0; g < GCC; ++g) s += mg[g] * wr[g];
    kccB[idx] = f2bf(s);
}

// ---------------- K3: wB = LDS image [gc][ks][tap][nj][l31][lhi][j] -------
__global__ __launch_bounds__(256) void k_wb(const float* __restrict__ w_kgl,
                                            u16* __restrict__ wB) {
    int idx = blockIdx.x * 256 + threadIdx.x;
    if (idx >= 36864) return;
    int j   = idx & 7;
    int lhi = (idx >> 3) & 1;
    int l   = (idx >> 4) & 31;
    int nj  = (idx >> 9) & 1;
    int t   = idx >> 10;          // (gc*2+ks)*9 + tap
    int tap = t % 9, gk = t / 9;
    int ks = gk & 1, gc = gk >> 1;
    int cout = nj * 32 + l;
    int g = gc * 32 + ks * 16 + lhi * 8 + j;
    wB[idx] = f2bf(w_kgl[((size_t)(cout * 64 + g)) * 9 + tap]);
}

// ---------------- K4: data -> dataC bf16 chunk-major (R7 data branch) -----
__global__ __launch_bounds__(256) void k_trc(const float* __restrict__ data,
                                             u16* __restrict__ dataC, int b0) {
    int w0 = blockIdx.x * 64;
    int h  = blockIdx.y;
    int bi = blockIdx.z;
    int bg = b0 + bi;
    int tid = threadIdx.x;
    __shared__ u16 tile[64][68];
    const float* src = data + ((size_t)bg * CINC) * HWSZ + (size_t)h * WW + w0;
    #pragma unroll
    for (int k = 0; k < 4; ++k) {
        int i = tid + k * 256;               // c*16 + wq
        int c = i >> 4, wq = i & 15;
        float4 v = *(const float4*)(src + (size_t)c * HWSZ + wq * 4);
        tile[c][wq * 4 + 0] = f2bf(v.x);
        tile[c][wq * 4 + 1] = f2bf(v.y);
        tile[c][wq * 4 + 2] = f2bf(v.z);
        tile[c][wq * 4 + 3] = f2bf(v.w);
    }
    __syncthreads();
    u16* dst = dataC + (size_t)bi * HWSZ * CINC;
    #pragma unroll
    for (int k = 0; k < 2; ++k) {
        int i = tid + k * 256;               // w*8 + g8 (c-octet)
        int w = i >> 3, g8 = i & 7;
        union { u16 s[8]; u32x4 v; } t;
        #pragma unroll
        for (int j = 0; j < 8; ++j) t.s[j] = tile[g8 * 8 + j][w];
        size_t px = (size_t)h * WW + w0 + w;
        *(u32x4*)(dst + ((size_t)(g8 >> 1) * HWSZ + px) * 16 + (g8 & 1) * 8) = t.v;
    }
}

// ---------------- K5: MFMA conv, A staged from RAW guid (bisection delta) -
// Everything else identical to R7 (16-wide kerC epilogue, swzA key).
__global__ __launch_bounds__(384) void k_convm(const float* __restrict__ guid,
                                               const u16* __restrict__ wB,
                                               const float* __restrict__ b_kgl,
                                               u16* __restrict__ ker, int b0) {
    int xt = blockIdx.x, rt = blockIdx.y, bi = blockIdx.z;
    int bg = b0 + bi;
    int tid = threadIdx.x;
    int x0 = xt * 64, oy0 = rt * 6;
    __shared__ __align__(16) u16 ldsA[8 * 66 * 32];        // 33792 B
    __shared__ __align__(16) u16 ldsB[9 * 2 * 32 * 16];    // 18432 B

    int wv = tid >> 6, lane = tid & 63;
    int l31 = lane & 31, lhi = lane >> 5;
    f32x16 acc[2][2] = {};    // [s(px-half)][nj(cout-half)]

    for (int gc = 0; gc < 2; ++gc) {
        for (int ks = 0; ks < 2; ++ks) {
            if (gc | ks) __syncthreads();
            // ---- stage B: linear 18432 B copy (R7-verified)
            const u16* bsrc = wB + (gc * 2 + ks) * 9216;
            #pragma unroll
            for (int k = 0; k < 3; ++k) {
                int i = tid + k * 384;
                *(u32x4*)(ldsB + (size_t)i * 8) = *(const u32x4*)(bsrc + (size_t)i * 8);
            }
            // ---- stage A from RAW guidance f32 (fused transpose + pack)
            if (ks == 0) {
                const float* gbase = guid + ((size_t)bg * 64 + gc * 32) * HWSZ;
                for (int i = tid; i < 544; i += 384) {
                    int qa = i % 17;
                    int rem = i / 17;
                    int go = rem & 3, rr = rem >> 2;
                    int iy = oy0 - 2 + rr;
                    int ix0 = x0 - 4 + 4 * qa;
                    union { float4 q; float f[4]; } va[8];
                    bool rowok = (iy >= 0) & (iy < HH);
                    if (rowok & (ix0 >= 0) & (ix0 + 3 < WW)) {
                        #pragma unroll
                        for (int j = 0; j < 8; ++j)
                            va[j].q = *(const float4*)(gbase + (size_t)(go * 8 + j) * HWSZ
                                                       + (size_t)iy * WW + ix0);
                    } else {
                        #pragma unroll
                        for (int j = 0; j < 8; ++j)
                            #pragma unroll
                            for (int t = 0; t < 4; ++t) {
                                int ix = ix0 + t;
                                va[j].f[t] = (rowok & (ix >= 0) & (ix < WW))
                                    ? gbase[(size_t)(go * 8 + j) * HWSZ + (size_t)iy * WW + ix]
                                    : 0.f;
                            }
                    }
                    #pragma unroll
                    for (int t = 0; t < 4; ++t) {
                        int cc = 4 * qa - 2 + t;
                        if (cc >= 0 && cc < 66) {
                            u32x4 wvv;
                            wvv[0] = pk2bf(va[0].f[t], va[1].f[t]);
                            wvv[1] = pk2bf(va[2].f[t], va[3].f[t]);
                            wvv[2] = pk2bf(va[4].f[t], va[5].f[t]);
                            wvv[3] = pk2bf(va[6].f[t], va[7].f[t]);
                            unsigned off = ((unsigned)((rr * 66 + cc) * 4 + go) * 16u)
                                           ^ swzA(cc);
                            *(u32x4*)((char*)ldsA + off) = wvv;
                        }
                    }
                }
            }
            __syncthreads();

            // ---- compute: 9 taps x 2 s x 2 nj (36 MFMA)  [R7-verified]
            for (int tap = 0; tap < 9; ++tap) {
                int di = tap / 3, dj = tap - di * 3;
                short8v Bf[2];
                #pragma unroll
                for (int nj = 0; nj < 2; ++nj)
                    Bf[nj] = *(const short8v*)(ldsB +
                        (((size_t)tap * 2 + nj) * 32 + l31) * 16 + lhi * 8);
                int rrow = wv + di;
                #pragma unroll
                for (int s = 0; s < 2; ++s) {
                    int cc = s * 32 + l31 + dj;
                    unsigned off = ((unsigned)((rrow * 66 + cc) * 4 + ks * 2 + lhi) * 16u)
                                   ^ swzA(cc);
                    short8v a = *(const short8v*)((const char*)ldsA + off);
                    acc[s][0] = __builtin_amdgcn_mfma_f32_32x32x16_bf16(a, Bf[0], acc[s][0], 0, 0, 0);
                    acc[s][1] = __builtin_amdgcn_mfma_f32_32x32x16_bf16(a, Bf[1], acc[s][1], 0, 0, 0);
                }
            }
        }
    }

    int oy = oy0 + wv;
    if (oy < HP) {
        float bias0 = b_kgl[l31], bias1 = b_kgl[32 + l31];
        u16* kout = ker + (size_t)bi * HWPSZ * GCC;
        int ckl = l31 >> 4, idx = l31 & 15;
        #pragma unroll
        for (int s = 0; s < 2; ++s)
            #pragma unroll
            for (int r = 0; r < 16; ++r) {
                int pxc = x0 + s * 32 + (r & 3) + 8 * (r >> 2) + 4 * lhi;
                if (pxc < WP) {
                    size_t pix = (size_t)oy * WP + pxc;
                    kout[((size_t)ckl * HWPSZ + pix) * 16 + idx]       = f2bf(acc[s][0][r] + bias0);
                    kout[((size_t)(2 + ckl) * HWPSZ + pix) * 16 + idx] = f2bf(acc[s][1][r] + bias1);
                }
            }
    }
}

// ---------------- K6: k_mix — R7 VERBATIM (prod staging + MFMA + BN) ------
__global__ __launch_bounds__(384) void k_mix(const u16* __restrict__ dataC,
                                             const u16* __restrict__ ker,
                                             const u16* __restrict__ kccB,
                                             float* __restrict__ out,
                                             float* __restrict__ stats, int b0) {
    int xt = blockIdx.x, rt = blockIdx.y, bi = blockIdx.z;
    int b = b0 + bi;
    int w0 = xt * 64, oy0 = rt * 6;
    int tid = threadIdx.x, wv = tid >> 6, lane = tid & 63;
    int l31 = lane & 31, lhi = lane >> 5;

    __shared__ __align__(16) float prd[2 * 528 * 8];   // 33792 B
    __shared__ float bsum[64], bsq[64];

    if (tid < 64) { bsum[tid] = 0.f; bsq[tid] = 0.f; }

    const u16* kerb = ker + (size_t)bi * HWPSZ * GCC;
    const u16* datb = dataC + (size_t)bi * HWSZ * CINC;
    const u16* kcb  = kccB + (size_t)b * COUTC * CINC;

    f32x16 acc[2][2] = {};    // [nj(o-half)][s(px-half)]

    for (int ck = 0; ck < 4; ++ck) {
        if (ck) __syncthreads();
        #pragma unroll
        for (int t = tid; t < 1056; t += 384) {
            int c2 = t & 1, px = t >> 1;
            int r = px / 66, cc = px - r * 66;
            int u = oy0 + r, kcol = w0 + cc;
            int iu = u - 1, iv = kcol - 1;
            float pr[8];
            if (u < HP && iu >= 0 && iu < HH && iv >= 0 && iv < WW) {
                u32x4 kv = *(const u32x4*)(kerb + ((size_t)ck * HWPSZ + (size_t)u * WP + kcol) * 16 + c2 * 8);
                u32x4 dv = *(const u32x4*)(datb + ((size_t)ck * HWSZ + (size_t)iu * WW + iv) * 16 + c2 * 8);
                const unsigned* kw = (const unsigned*)&kv;
                const unsigned* dw = (const unsigned*)&dv;
                #pragma unroll
                for (int p = 0; p < 4; ++p) {
                    pr[2 * p]     = __uint_as_float(kw[p] << 16) * __uint_as_float(dw[p] << 16);
                    pr[2 * p + 1] = __uint_as_float(kw[p] & 0xffff0000u) * __uint_as_float(dw[p] & 0xffff0000u);
                }
            } else {
                #pragma unroll
                for (int j = 0; j < 8; ++j) pr[j] = 0.f;
            }
            float* pp = prd + c2 * 4224 + px * 8;
            *(float4*)pp       = make_float4(pr[0], pr[1], pr[2], pr[3]);
            *(float4*)(pp + 4) = make_float4(pr[4], pr[5], pr[6], pr[7]);
        }
        __syncthreads();

        short8v ka0 = *(const short8v*)(kcb + ((size_t)l31 * 64 + ck * 16 + lhi * 8));
        short8v ka1 = *(const short8v*)(kcb + ((size_t)(32 + l31) * 64 + ck * 16 + lhi * 8));

        #pragma unroll
        for (int s = 0; s < 2; ++s) {
            float x1v[8];
            #pragma unroll
            for (int j = 0; j < 8; ++j) x1v[j] = 0.f;
            #pragma unroll
            for (int di = 0; di < 3; ++di) {
                int row = wv + di;
                #pragma unroll
                for (int dj = 0; dj < 3; ++dj) {
                    int col = s * 32 + l31 + dj;
                    const float* pp = prd + lhi * 4224 + (row * 66 + col) * 8;
                    float4 a0 = *(const float4*)pp;
                    float4 a1 = *(const float4*)(pp + 4);
                    x1v[0] += a0.x; x1v[1] += a0.y; x1v[2] += a0.z; x1v[3] += a0.w;
                    x1v[4] += a1.x; x1v[5] += a1.y; x1v[6] += a1.z; x1v[7] += a1.w;
                }
            }
            union { u16 h[8]; short8v v8; } xb;
            #pragma unroll
            for (int j = 0; j < 8; ++j) xb.h[j] = f2bf(x1v[j]);
            acc[0][s] = __builtin_amdgcn_mfma_f32_32x32x16_bf16(ka0, xb.v8, acc[0][s], 0, 0, 0);
            acc[1][s] = __builtin_amdgcn_mfma_f32_32x32x16_bf16(ka1, xb.v8, acc[1][s], 0, 0, 0);
        }
    }

    int oy = oy0 + wv;
    if (oy < HH) {
        #pragma unroll
        for (int nj = 0; nj < 2; ++nj)
            #pragma unroll
            for (int r = 0; r < 16; ++r) {
                int o = nj * 32 + (r & 3) + 8 * (r >> 2) + 4 * lhi;
                float v0 = acc[nj][0][r]; v0 = v0 > 0.f ? v0 : LEAK * v0;
                float v1 = acc[nj][1][r]; v1 = v1 > 0.f ? v1 : LEAK * v1;
                size_t rowb = ((size_t)(b * COUTC + o)) * HWSZ + (size_t)oy * WW + w0;
                out[rowb + l31]      = v0;
                out[rowb + 32 + l31] = v1;
                float ss = v0 + v1, qq = v0 * v0 + v1 * v1;
                #pragma unroll
                for (int off = 16; off; off >>= 1) {
                    ss += __shfl_xor(ss, off);
                    qq += __shfl_xor(qq, off);
                }
                if (l31 == 0) { atomicAdd(&bsum[o], ss); atomicAdd(&bsq[o], qq); }
            }
    }
    __syncthreads();
    int rep = (blockIdx.x + blockIdx.y * 5 + blockIdx.z * 3) & 7;
    if (tid < 64) {
        atomicAdd(&stats[rep * 128 + tid], bsum[tid]);
        atomicAdd(&stats[rep * 128 + 64 + tid], bsq[tid]);
    }
}

__global__ void k_fin(const float* __restrict__ stats,
                      const float* __restrict__ gamma, const float* __restrict__ beta,
                      float* __restrict__ scale, float* __restrict__ shift) {
    int o = threadIdx.x;
    float s = 0.f, q = 0.f;
    #pragma unroll
    for (int r = 0; r < 8; ++r) { s += stats[r * 128 + o]; q += stats[r * 128 + 64 + o]; }
    float n = (float)BB * (float)HWSZ;
    float mu = s / n;
    float var = q / n - mu * mu;
    float rs = rsqrtf(var + EPSB);
    float sc = rs * gamma[o];
    scale[o] = sc;
    shift[o] = beta[o] - mu * sc;
}

__global__ __launch_bounds__(256) void k_norm(float* __restrict__ x,
                                              const float* __restrict__ scale,
                                              const float* __restrict__ shift) {
    size_t i = (size_t)blockIdx.x * 256 + threadIdx.x;
    int ch = (int)((i * 4) / HWSZ) & 63;
    float4 v = ((float4*)x)[i];
    float sc = scale[ch], sh = shift[ch];
    v.x = v.x * sc + sh; v.y = v.y * sc + sh; v.z = v.z * sc + sh; v.w = v.w * sc + sh;
    ((float4*)x)[i] = v;
}

extern "C" void kernel_launch(void* const* d_in, const int* in_sizes, int n_in,
                              void* d_out, int out_size, void* d_ws, size_t ws_size,
                              hipStream_t stream) {
    const float* data  = (const float*)d_in[0];
    const float* guid  = (const float*)d_in[1];
    const float* w_kgl = (const float*)d_in[2];
    const float* b_kgl = (const float*)d_in[3];
    const float* w_cc  = (const float*)d_in[4];
    const float* b_cc  = (const float*)d_in[5];
    const float* gamma = (const float*)d_in[6];
    const float* beta  = (const float*)d_in[7];
    float* out = (float*)d_out;
    float* ws  = (float*)d_ws;

    // ws (f32): [mean_g 512][stats 8*128][scale 64][shift 64] = 1664
    // then u16: [kccB 32768][wB 36864][dataC bs*HWSZ*64][kerC bs*HWPSZ*64]
    float* mean_g = ws;
    float* stats  = ws + 512;
    float* scale  = stats + 1024;
    float* shift  = scale + 64;
    u16*   kccB   = (u16*)(ws + 1664);
    u16*   wB     = kccB + BB * 4096;
    u16*   dataC  = wB + 36864;

    size_t used_us = 1664 * 2 + BB * 4096 + 36864;
    size_t cap_us  = (ws_size / 2 > used_us) ? ws_size / 2 - used_us : 0;
    size_t per_b   = (size_t)GCC * (HWSZ + HWPSZ);
    // bs=4: dataC+kerC chunk = 105 MB, L3-resident
    int bs = 4;
    while (bs > 1 && (size_t)bs * per_b > cap_us) bs >>= 1;
    u16* kerC = dataC + (size_t)bs * HWSZ * GCC;

    hipMemsetAsync(stats, 0, 1024 * sizeof(float), stream);
    k_mean<<<BB * GCC, 256, 0, stream>>>(guid, mean_g);
    k_kcc<<<(BB * COUTC * CINC + 255) / 256, 256, 0, stream>>>(mean_g, w_cc, b_cc, kccB);
    k_wb<<<144, 256, 0, stream>>>(w_kgl, wB);

    for (int b0 = 0; b0 < BB; b0 += bs) {
        int nb = (BB - b0 < bs) ? BB - b0 : bs;
        k_trc<<<dim3(WW / 64, HH, nb), 256, 0, stream>>>(data, dataC, b0);
        k_convm<<<dim3(6, 54, nb), 384, 0, stream>>>(guid, wB, b_kgl, kerC, b0);
        k_mix<<<dim3(5, 54, nb), 384, 0, stream>>>(dataC, kerC, kccB, out, stats, b0);
    }
    k_fin<<<1, 64, 0, stream>>>(stats, gamma, beta, scale, shift);
    k_norm<<<(out_size / 4 + 255) / 256, 256, 0, stream>>>(out, scale, shift);
}

// Round 12
// 604.127 us; speedup vs baseline: 5.7590x; 1.0681x over previous
//
#include <hip/hip_runtime.h>

#define BB 8
#define CINC 64
#define COUTC 64
#define GCC 64
#define HH 320
#define WW 320
#define HP 322
#define WP 322
#define LEAK 0.2f
#define EPSB 1e-5f
#define HWSZ (HH*WW)
#define HWPSZ (HP*WP)

typedef unsigned short u16;
typedef __attribute__((ext_vector_type(8))) short short8v;   // 8 bf16
typedef __attribute__((ext_vector_type(16))) float f32x16;   // MFMA 32x32 acc
typedef __attribute__((ext_vector_type(4))) unsigned int u32x4;

static __device__ __forceinline__ u16 f2bf(float f) {
    unsigned u = __float_as_uint(f);
    u += 0x7fffu + ((u >> 16) & 1u);      // RNE
    return (u16)(u >> 16);
}
static __device__ __forceinline__ unsigned pk2bf(float a, float b) {
    return (unsigned)f2bf(a) | ((unsigned)f2bf(b) << 16);
}
// A-tile LDS swizzle (R6/R7-verified key)
static __device__ __forceinline__ unsigned swzA(int cc) {
    return (unsigned)((((cc >> 1) & 1) << 5) | (((cc >> 2) & 1) << 4));
}
// prd swizzle key: WINDOW-indexed (px>>2 = 128B-window id) -> constant within
// each window -> XOR permutes bits 4-6 inside the window -> bijective by
// construction (fixes R11's odd-row cc-quad straddle collision).
static __device__ __forceinline__ unsigned swzP(int px) {
    return ((unsigned)(px >> 2) & 7u) << 4;
}

// ---------------- K1: per-(b,g) mean of guidance ----------------
__global__ __launch_bounds__(256) void k_mean(const float* __restrict__ g,
                                              float* __restrict__ mean_g) {
    int row = blockIdx.x;                       // b*GC + gc
    const float4* p = (const float4*)(g + (size_t)row * HWSZ);
    float s = 0.f;
    for (int i = threadIdx.x; i < HWSZ / 4; i += 256) {
        float4 v = p[i];
        s += v.x + v.y + v.z + v.w;
    }
    #pragma unroll
    for (int off = 32; off; off >>= 1) s += __shfl_down(s, off);
    __shared__ float ls[4];
    if ((threadIdx.x & 63) == 0) ls[threadIdx.x >> 6] = s;
    __syncthreads();
    if (threadIdx.x == 0)
        mean_g[row] = (ls[0] + ls[1] + ls[2] + ls[3]) * (1.f / (float)HWSZ);
}

// ---------------- K2: kccB[b][o][c] bf16 ----------------
__global__ __launch_bounds__(256) void k_kcc(const float* __restrict__ mean_g,
                                             const float* __restrict__ w_cc,
                                             const float* __restrict__ b_cc,
                                             u16* __restrict__ kccB) {
    int idx = blockIdx.x * 256 + threadIdx.x;
    if (idx >= BB * COUTC * CINC) return;
    int b = idx >> 12;
    int j = idx & 4095;                  // o*64 + c
    const float* mg = mean_g + b * GCC;
    const float* wr = w_cc + (size_t)j * GCC;
    float s = b_cc[j];
    #pragma unroll
    for (int g = 0; g < GCC; ++g) s += mg[g] * wr[g];
    kccB[idx] = f2bf(s);
}

// ---------------- K3: wB = LDS image [gc][ks][tap][nj][l31][lhi][j] -------
__global__ __launch_bounds__(256) void k_wb(const float* __restrict__ w_kgl,
                                            u16* __restrict__ wB) {
    int idx = blockIdx.x * 256 + threadIdx.x;
    if (idx >= 36864) return;
    int j   = idx & 7;
    int lhi = (idx >> 3) & 1;
    int l   = (idx >> 4) & 31;
    int nj  = (idx >> 9) & 1;
    int t   = idx >> 10;          // (gc*2+ks)*9 + tap
    int tap = t % 9, gk = t / 9;
    int ks = gk & 1, gc = gk >> 1;
    int cout = nj * 32 + l;
    int g = gc * 32 + ks * 16 + lhi * 8 + j;
    wB[idx] = f2bf(w_kgl[((size_t)(cout * 64 + g)) * 9 + tap]);
}

// ---------------- K4: data -> dataC bf16 chunk-major ----------------------
__global__ __launch_bounds__(256) void k_trc(const float* __restrict__ data,
                                             u16* __restrict__ dataC, int b0) {
    int w0 = blockIdx.x * 64;
    int h  = blockIdx.y;
    int bi = blockIdx.z;
    int bg = b0 + bi;
    int tid = threadIdx.x;
    __shared__ u16 tile[64][68];
    const float* src = data + ((size_t)bg * CINC) * HWSZ + (size_t)h * WW + w0;
    #pragma unroll
    for (int k = 0; k < 4; ++k) {
        int i = tid + k * 256;               // c*16 + wq
        int c = i >> 4, wq = i & 15;
        float4 v = *(const float4*)(src + (size_t)c * HWSZ + wq * 4);
        tile[c][wq * 4 + 0] = f2bf(v.x);
        tile[c][wq * 4 + 1] = f2bf(v.y);
        tile[c][wq * 4 + 2] = f2bf(v.z);
        tile[c][wq * 4 + 3] = f2bf(v.w);
    }
    __syncthreads();
    u16* dst = dataC + (size_t)bi * HWSZ * CINC;
    #pragma unroll
    for (int k = 0; k < 2; ++k) {
        int i = tid + k * 256;               // w*8 + g8 (c-octet)
        int w = i >> 3, g8 = i & 7;
        union { u16 s[8]; u32x4 v; } t;
        #pragma unroll
        for (int j = 0; j < 8; ++j) t.s[j] = tile[g8 * 8 + j][w];
        size_t px = (size_t)h * WW + w0 + w;
        *(u32x4*)(dst + ((size_t)(g8 >> 1) * HWSZ + px) * 16 + (g8 & 1) * 8) = t.v;
    }
}

// ---------------- K5: MFMA conv, A staged from RAW guid (R10-verified) ----
__global__ __launch_bounds__(384) void k_convm(const float* __restrict__ guid,
                                               const u16* __restrict__ wB,
                                               const float* __restrict__ b_kgl,
                                               u16* __restrict__ ker, int b0) {
    int xt = blockIdx.x, rt = blockIdx.y, bi = blockIdx.z;
    int bg = b0 + bi;
    int tid = threadIdx.x;
    int x0 = xt * 64, oy0 = rt * 6;
    __shared__ __align__(16) u16 ldsA[8 * 66 * 32];        // 33792 B
    __shared__ __align__(16) u16 ldsB[9 * 2 * 32 * 16];    // 18432 B

    int wv = tid >> 6, lane = tid & 63;
    int l31 = lane & 31, lhi = lane >> 5;
    f32x16 acc[2][2] = {};    // [s(px-half)][nj(cout-half)]

    for (int gc = 0; gc < 2; ++gc) {
        for (int ks = 0; ks < 2; ++ks) {
            if (gc | ks) __syncthreads();
            // ---- stage B: linear 18432 B copy
            const u16* bsrc = wB + (gc * 2 + ks) * 9216;
            #pragma unroll
            for (int k = 0; k < 3; ++k) {
                int i = tid + k * 384;
                *(u32x4*)(ldsB + (size_t)i * 8) = *(const u32x4*)(bsrc + (size_t)i * 8);
            }
            // ---- stage A from RAW guidance f32 (fused transpose + pack)
            if (ks == 0) {
                const float* gbase = guid + ((size_t)bg * 64 + gc * 32) * HWSZ;
                for (int i = tid; i < 544; i += 384) {
                    int qa = i % 17;
                    int rem = i / 17;
                    int go = rem & 3, rr = rem >> 2;
                    int iy = oy0 - 2 + rr;
                    int ix0 = x0 - 4 + 4 * qa;
                    union { float4 q; float f[4]; } va[8];
                    bool rowok = (iy >= 0) & (iy < HH);
                    if (rowok & (ix0 >= 0) & (ix0 + 3 < WW)) {
                        #pragma unroll
                        for (int j = 0; j < 8; ++j)
                            va[j].q = *(const float4*)(gbase + (size_t)(go * 8 + j) * HWSZ
                                                       + (size_t)iy * WW + ix0);
                    } else {
                        #pragma unroll
                        for (int j = 0; j < 8; ++j)
                            #pragma unroll
                            for (int t = 0; t < 4; ++t) {
                                int ix = ix0 + t;
                                va[j].f[t] = (rowok & (ix >= 0) & (ix < WW))
                                    ? gbase[(size_t)(go * 8 + j) * HWSZ + (size_t)iy * WW + ix]
                                    : 0.f;
                            }
                    }
                    #pragma unroll
                    for (int t = 0; t < 4; ++t) {
                        int cc = 4 * qa - 2 + t;
                        if (cc >= 0 && cc < 66) {
                            u32x4 wvv;
                            wvv[0] = pk2bf(va[0].f[t], va[1].f[t]);
                            wvv[1] = pk2bf(va[2].f[t], va[3].f[t]);
                            wvv[2] = pk2bf(va[4].f[t], va[5].f[t]);
                            wvv[3] = pk2bf(va[6].f[t], va[7].f[t]);
                            unsigned off = ((unsigned)((rr * 66 + cc) * 4 + go) * 16u)
                                           ^ swzA(cc);
                            *(u32x4*)((char*)ldsA + off) = wvv;
                        }
                    }
                }
            }
            __syncthreads();

            // ---- compute: 9 taps x 2 s x 2 nj (36 MFMA)
            for (int tap = 0; tap < 9; ++tap) {
                int di = tap / 3, dj = tap - di * 3;
                short8v Bf[2];
                #pragma unroll
                for (int nj = 0; nj < 2; ++nj)
                    Bf[nj] = *(const short8v*)(ldsB +
                        (((size_t)tap * 2 + nj) * 32 + l31) * 16 + lhi * 8);
                int rrow = wv + di;
                #pragma unroll
                for (int s = 0; s < 2; ++s) {
                    int cc = s * 32 + l31 + dj;
                    unsigned off = ((unsigned)((rrow * 66 + cc) * 4 + ks * 2 + lhi) * 16u)
                                   ^ swzA(cc);
                    short8v a = *(const short8v*)((const char*)ldsA + off);
                    acc[s][0] = __builtin_amdgcn_mfma_f32_32x32x16_bf16(a, Bf[0], acc[s][0], 0, 0, 0);
                    acc[s][1] = __builtin_amdgcn_mfma_f32_32x32x16_bf16(a, Bf[1], acc[s][1], 0, 0, 0);
                }
            }
        }
    }

    int oy = oy0 + wv;
    if (oy < HP) {
        float bias0 = b_kgl[l31], bias1 = b_kgl[32 + l31];
        u16* kout = ker + (size_t)bi * HWPSZ * GCC;
        int ckl = l31 >> 4, idx = l31 & 15;
        #pragma unroll
        for (int s = 0; s < 2; ++s)
            #pragma unroll
            for (int r = 0; r < 16; ++r) {
                int pxc = x0 + s * 32 + (r & 3) + 8 * (r >> 2) + 4 * lhi;
                if (pxc < WP) {
                    size_t pix = (size_t)oy * WP + pxc;
                    kout[((size_t)ckl * HWPSZ + pix) * 16 + idx]       = f2bf(acc[s][0][r] + bias0);
                    kout[((size_t)(2 + ckl) * HWPSZ + pix) * 16 + idx] = f2bf(acc[s][1][r] + bias1);
                }
            }
    }
}

// ---------------- K6: k_mix — window-keyed swizzled prd + async-STAGE -----
// Same as R11 except the prd XOR key is swzP(px) (window-indexed, proven
// bijective) instead of the cc-based key (which collided on odd rows).
__global__ __launch_bounds__(384) void k_mix(const u16* __restrict__ dataC,
                                             const u16* __restrict__ ker,
                                             const u16* __restrict__ kccB,
                                             float* __restrict__ out,
                                             float* __restrict__ stats, int b0) {
    int xt = blockIdx.x, rt = blockIdx.y, bi = blockIdx.z;
    int b = b0 + bi;
    int w0 = xt * 64, oy0 = rt * 6;
    int tid = threadIdx.x, wv = tid >> 6, lane = tid & 63;
    int l31 = lane & 31, lhi = lane >> 5;

    __shared__ __align__(16) float prd[2 * 528 * 8];   // 33792 B
    __shared__ float bsum[64], bsq[64];

    if (tid < 64) { bsum[tid] = 0.f; bsq[tid] = 0.f; }

    const u16* kerb = ker + (size_t)bi * HWPSZ * GCC;
    const u16* datb = dataC + (size_t)bi * HWSZ * CINC;
    const u16* kcb  = kccB + (size_t)b * COUTC * CINC;

    f32x16 acc[2][2] = {};    // [nj(o-half)][s(px-half)]
    u32x4 kvr[3], dvr[3];

#define MIX_LOAD(CK)                                                          \
    {                                                                         \
        _Pragma("unroll")                                                     \
        for (int it = 0; it < 3; ++it) {                                      \
            int t = tid + it * 384;                                           \
            if (t < 1056) {                                                   \
                int c2 = t & 1, px = t >> 1;                                  \
                int r = px / 66, cc = px - r * 66;                            \
                int u = oy0 + r, kcol = w0 + cc;                              \
                int iu = u - 1, iv = kcol - 1;                                \
                u32x4 kz = {0, 0, 0, 0}, dz = {0, 0, 0, 0};                   \
                if (u < HP && iu >= 0 && iu < HH && iv >= 0 && iv < WW) {     \
                    kz = *(const u32x4*)(kerb + ((size_t)(CK) * HWPSZ + (size_t)u * WP + kcol) * 16 + c2 * 8); \
                    dz = *(const u32x4*)(datb + ((size_t)(CK) * HWSZ + (size_t)iu * WW + iv) * 16 + c2 * 8);   \
                }                                                             \
                kvr[it] = kz; dvr[it] = dz;                                   \
            }                                                                 \
        }                                                                     \
    }

    MIX_LOAD(0);

    #pragma unroll
    for (int ck = 0; ck < 4; ++ck) {
        if (ck) __syncthreads();                 // prev compute done reading prd
        // ---- write staged regs -> prd (window-keyed XOR swizzle)
        #pragma unroll
        for (int it = 0; it < 3; ++it) {
            int t = tid + it * 384;
            if (t < 1056) {
                int c2 = t & 1, px = t >> 1;
                float pr[8];
                #pragma unroll
                for (int p = 0; p < 4; ++p) {
                    pr[2 * p]     = __uint_as_float(kvr[it][p] << 16) * __uint_as_float(dvr[it][p] << 16);
                    pr[2 * p + 1] = __uint_as_float(kvr[it][p] & 0xffff0000u) * __uint_as_float(dvr[it][p] & 0xffff0000u);
                }
                unsigned fo = (unsigned)((c2 * 4224 + px * 8) * 4);
                unsigned x = swzP(px);
                *(float4*)((char*)prd + (fo ^ x))        = make_float4(pr[0], pr[1], pr[2], pr[3]);
                *(float4*)((char*)prd + ((fo + 16) ^ x)) = make_float4(pr[4], pr[5], pr[6], pr[7]);
            }
        }
        __syncthreads();
        if (ck < 3) MIX_LOAD(ck + 1);            // prefetch next chunk (T14)

        // ---- compute: box-sum from swizzled prd + MFMA mix
        short8v ka0 = *(const short8v*)(kcb + ((size_t)l31 * 64 + ck * 16 + lhi * 8));
        short8v ka1 = *(const short8v*)(kcb + ((size_t)(32 + l31) * 64 + ck * 16 + lhi * 8));

        #pragma unroll
        for (int s = 0; s < 2; ++s) {
            float x1v[8];
            #pragma unroll
            for (int j = 0; j < 8; ++j) x1v[j] = 0.f;
            #pragma unroll
            for (int di = 0; di < 3; ++di) {
                int row = wv + di;
                #pragma unroll
                for (int dj = 0; dj < 3; ++dj) {
                    int col = s * 32 + l31 + dj;
                    int px = row * 66 + col;
                    unsigned fo = (unsigned)((lhi * 4224 + px * 8) * 4);
                    unsigned x = swzP(px);
                    float4 a0 = *(const float4*)((const char*)prd + (fo ^ x));
                    float4 a1 = *(const float4*)((const char*)prd + ((fo + 16) ^ x));
                    x1v[0] += a0.x; x1v[1] += a0.y; x1v[2] += a0.z; x1v[3] += a0.w;
                    x1v[4] += a1.x; x1v[5] += a1.y; x1v[6] += a1.z; x1v[7] += a1.w;
                }
            }
            union { u16 h[8]; short8v v8; } xb;
            #pragma unroll
            for (int j = 0; j < 8; ++j) xb.h[j] = f2bf(x1v[j]);
            acc[0][s] = __builtin_amdgcn_mfma_f32_32x32x16_bf16(ka0, xb.v8, acc[0][s], 0, 0, 0);
            acc[1][s] = __builtin_amdgcn_mfma_f32_32x32x16_bf16(ka1, xb.v8, acc[1][s], 0, 0, 0);
        }
    }
#undef MIX_LOAD

    int oy = oy0 + wv;
    if (oy < HH) {
        #pragma unroll
        for (int nj = 0; nj < 2; ++nj)
            #pragma unroll
            for (int r = 0; r < 16; ++r) {
                int o = nj * 32 + (r & 3) + 8 * (r >> 2) + 4 * lhi;
                float v0 = acc[nj][0][r]; v0 = v0 > 0.f ? v0 : LEAK * v0;
                float v1 = acc[nj][1][r]; v1 = v1 > 0.f ? v1 : LEAK * v1;
                size_t rowb = ((size_t)(b * COUTC + o)) * HWSZ + (size_t)oy * WW + w0;
                out[rowb + l31]      = v0;
                out[rowb + 32 + l31] = v1;
                float ss = v0 + v1, qq = v0 * v0 + v1 * v1;
                #pragma unroll
                for (int off = 16; off; off >>= 1) {
                    ss += __shfl_xor(ss, off);
                    qq += __shfl_xor(qq, off);
                }
                if (l31 == 0) { atomicAdd(&bsum[o], ss); atomicAdd(&bsq[o], qq); }
            }
    }
    __syncthreads();
    int rep = (blockIdx.x + blockIdx.y * 5 + blockIdx.z * 3) & 7;
    if (tid < 64) {
        atomicAdd(&stats[rep * 128 + tid], bsum[tid]);
        atomicAdd(&stats[rep * 128 + 64 + tid], bsq[tid]);
    }
}

__global__ void k_fin(const float* __restrict__ stats,
                      const float* __restrict__ gamma, const float* __restrict__ beta,
                      float* __restrict__ scale, float* __restrict__ shift) {
    int o = threadIdx.x;
    float s = 0.f, q = 0.f;
    #pragma unroll
    for (int r = 0; r < 8; ++r) { s += stats[r * 128 + o]; q += stats[r * 128 + 64 + o]; }
    float n = (float)BB * (float)HWSZ;
    float mu = s / n;
    float var = q / n - mu * mu;
    float rs = rsqrtf(var + EPSB);
    float sc = rs * gamma[o];
    scale[o] = sc;
    shift[o] = beta[o] - mu * sc;
}

__global__ __launch_bounds__(256) void k_norm(float* __restrict__ x,
                                              const float* __restrict__ scale,
                                              const float* __restrict__ shift) {
    size_t i = (size_t)blockIdx.x * 256 + threadIdx.x;
    int ch = (int)((i * 4) / HWSZ) & 63;
    float4 v = ((float4*)x)[i];
    float sc = scale[ch], sh = shift[ch];
    v.x = v.x * sc + sh; v.y = v.y * sc + sh; v.z = v.z * sc + sh; v.w = v.w * sc + sh;
    ((float4*)x)[i] = v;
}

extern "C" void kernel_launch(void* const* d_in, const int* in_sizes, int n_in,
                              void* d_out, int out_size, void* d_ws, size_t ws_size,
                              hipStream_t stream) {
    const float* data  = (const float*)d_in[0];
    const float* guid  = (const float*)d_in[1];
    const float* w_kgl = (const float*)d_in[2];
    const float* b_kgl = (const float*)d_in[3];
    const float* w_cc  = (const float*)d_in[4];
    const float* b_cc  = (const float*)d_in[5];
    const float* gamma = (const float*)d_in[6];
    const float* beta  = (const float*)d_in[7];
    float* out = (float*)d_out;
    float* ws  = (float*)d_ws;

    // ws (f32): [mean_g 512][stats 8*128][scale 64][shift 64] = 1664
    // then u16: [kccB 32768][wB 36864][dataC bs*HWSZ*64][kerC bs*HWPSZ*64]
    float* mean_g = ws;
    float* stats  = ws + 512;
    float* scale  = stats + 1024;
    float* shift  = scale + 64;
    u16*   kccB   = (u16*)(ws + 1664);
    u16*   wB     = kccB + BB * 4096;
    u16*   dataC  = wB + 36864;

    size_t used_us = 1664 * 2 + BB * 4096 + 36864;
    size_t cap_us  = (ws_size / 2 > used_us) ? ws_size / 2 - used_us : 0;
    size_t per_b   = (size_t)GCC * (HWSZ + HWPSZ);
    // bs=4: dataC+kerC chunk = 105 MB, L3-resident
    int bs = 4;
    while (bs > 1 && (size_t)bs * per_b > cap_us) bs >>= 1;
    u16* kerC = dataC + (size_t)bs * HWSZ * GCC;

    hipMemsetAsync(stats, 0, 1024 * sizeof(float), stream);
    k_mean<<<BB * GCC, 256, 0, stream>>>(guid, mean_g);
    k_kcc<<<(BB * COUTC * CINC + 255) / 256, 256, 0, stream>>>(mean_g, w_cc, b_cc, kccB);
    k_wb<<<144, 256, 0, stream>>>(w_kgl, wB);

    for (int b0 = 0; b0 < BB; b0 += bs) {
        int nb = (BB - b0 < bs) ? BB - b0 : bs;
        k_trc<<<dim3(WW / 64, HH, nb), 256, 0, stream>>>(data, dataC, b0);
        k_convm<<<dim3(6, 54, nb), 384, 0, stream>>>(guid, wB, b_kgl, kerC, b0);
        k_mix<<<dim3(5, 54, nb), 384, 0, stream>>>(dataC, kerC, kccB, out, stats, b0);
    }
    k_fin<<<1, 64, 0, stream>>>(stats, gamma, beta, scale, shift);
    k_norm<<<(out_size / 4 + 255) / 256, 256, 0, stream>>>(out, scale, shift);
}

// Round 13
// 579.949 us; speedup vs baseline: 5.9991x; 1.0417x over previous
//
#include <hip/hip_runtime.h>

#define BB 8
#define CINC 64
#define COUTC 64
#define GCC 64
#define HH 320
#define WW 320
#define HP 322
#define WP 322
#define LEAK 0.2f
#define EPSB 1e-5f
#define HWSZ (HH*WW)
#define HWPSZ (HP*WP)

typedef unsigned short u16;
typedef __attribute__((ext_vector_type(8))) short short8v;   // 8 bf16
typedef __attribute__((ext_vector_type(16))) float f32x16;   // MFMA 32x32 acc
typedef __attribute__((ext_vector_type(4))) unsigned int u32x4;

static __device__ __forceinline__ u16 f2bf(float f) {
    unsigned u = __float_as_uint(f);
    u += 0x7fffu + ((u >> 16) & 1u);      // RNE
    return (u16)(u >> 16);
}
static __device__ __forceinline__ unsigned pk2bf(float a, float b) {
    return (unsigned)f2bf(a) | ((unsigned)f2bf(b) << 16);
}
// A-tile LDS swizzle (R6/R7-verified key)
static __device__ __forceinline__ unsigned swzA(int cc) {
    return (unsigned)((((cc >> 1) & 1) << 5) | (((cc >> 2) & 1) << 4));
}
// prd swizzle key: window-indexed, bijective by construction (R12-verified)
static __device__ __forceinline__ unsigned swzP(int px) {
    return ((unsigned)(px >> 2) & 7u) << 4;
}

// ---------------- K1: per-(b,g) mean of guidance ----------------
__global__ __launch_bounds__(256) void k_mean(const float* __restrict__ g,
                                              float* __restrict__ mean_g) {
    int row = blockIdx.x;                       // b*GC + gc
    const float4* p = (const float4*)(g + (size_t)row * HWSZ);
    float s = 0.f;
    for (int i = threadIdx.x; i < HWSZ / 4; i += 256) {
        float4 v = p[i];
        s += v.x + v.y + v.z + v.w;
    }
    #pragma unroll
    for (int off = 32; off; off >>= 1) s += __shfl_down(s, off);
    __shared__ float ls[4];
    if ((threadIdx.x & 63) == 0) ls[threadIdx.x >> 6] = s;
    __syncthreads();
    if (threadIdx.x == 0)
        mean_g[row] = (ls[0] + ls[1] + ls[2] + ls[3]) * (1.f / (float)HWSZ);
}

// ---------------- K2: kccB[b][o][c] bf16 ----------------
__global__ __launch_bounds__(256) void k_kcc(const float* __restrict__ mean_g,
                                             const float* __restrict__ w_cc,
                                             const float* __restrict__ b_cc,
                                             u16* __restrict__ kccB) {
    int idx = blockIdx.x * 256 + threadIdx.x;
    if (idx >= BB * COUTC * CINC) return;
    int b = idx >> 12;
    int j = idx & 4095;                  // o*64 + c
    const float* mg = mean_g + b * GCC;
    const float* wr = w_cc + (size_t)j * GCC;
    float s = b_cc[j];
    #pragma unroll
    for (int g = 0; g < GCC; ++g) s += mg[g] * wr[g];
    kccB[idx] = f2bf(s);
}

// ---------------- K3: wB = LDS image [gc][ks][tap][nj][l31][lhi][j] -------
__global__ __launch_bounds__(256) void k_wb(const float* __restrict__ w_kgl,
                                            u16* __restrict__ wB) {
    int idx = blockIdx.x * 256 + threadIdx.x;
    if (idx >= 36864) return;
    int j   = idx & 7;
    int lhi = (idx >> 3) & 1;
    int l   = (idx >> 4) & 31;
    int nj  = (idx >> 9) & 1;
    int t   = idx >> 10;          // (gc*2+ks)*9 + tap
    int tap = t % 9, gk = t / 9;
    int ks = gk & 1, gc = gk >> 1;
    int cout = nj * 32 + l;
    int g = gc * 32 + ks * 16 + lhi * 8 + j;
    wB[idx] = f2bf(w_kgl[((size_t)(cout * 64 + g)) * 9 + tap]);
}

// ---------------- K5: MFMA conv, A staged from RAW guid (R10-verified) ----
__global__ __launch_bounds__(384) void k_convm(const float* __restrict__ guid,
                                               const u16* __restrict__ wB,
                                               const float* __restrict__ b_kgl,
                                               u16* __restrict__ ker, int b0) {
    int xt = blockIdx.x, rt = blockIdx.y, bi = blockIdx.z;
    int bg = b0 + bi;
    int tid = threadIdx.x;
    int x0 = xt * 64, oy0 = rt * 6;
    __shared__ __align__(16) u16 ldsA[8 * 66 * 32];        // 33792 B
    __shared__ __align__(16) u16 ldsB[9 * 2 * 32 * 16];    // 18432 B

    int wv = tid >> 6, lane = tid & 63;
    int l31 = lane & 31, lhi = lane >> 5;
    f32x16 acc[2][2] = {};    // [s(px-half)][nj(cout-half)]

    for (int gc = 0; gc < 2; ++gc) {
        for (int ks = 0; ks < 2; ++ks) {
            if (gc | ks) __syncthreads();
            // ---- stage B: linear 18432 B copy
            const u16* bsrc = wB + (gc * 2 + ks) * 9216;
            #pragma unroll
            for (int k = 0; k < 3; ++k) {
                int i = tid + k * 384;
                *(u32x4*)(ldsB + (size_t)i * 8) = *(const u32x4*)(bsrc + (size_t)i * 8);
            }
            // ---- stage A from RAW guidance f32 (fused transpose + pack)
            if (ks == 0) {
                const float* gbase = guid + ((size_t)bg * 64 + gc * 32) * HWSZ;
                for (int i = tid; i < 544; i += 384) {
                    int qa = i % 17;
                    int rem = i / 17;
                    int go = rem & 3, rr = rem >> 2;
                    int iy = oy0 - 2 + rr;
                    int ix0 = x0 - 4 + 4 * qa;
                    union { float4 q; float f[4]; } va[8];
                    bool rowok = (iy >= 0) & (iy < HH);
                    if (rowok & (ix0 >= 0) & (ix0 + 3 < WW)) {
                        #pragma unroll
                        for (int j = 0; j < 8; ++j)
                            va[j].q = *(const float4*)(gbase + (size_t)(go * 8 + j) * HWSZ
                                                       + (size_t)iy * WW + ix0);
                    } else {
                        #pragma unroll
                        for (int j = 0; j < 8; ++j)
                            #pragma unroll
                            for (int t = 0; t < 4; ++t) {
                                int ix = ix0 + t;
                                va[j].f[t] = (rowok & (ix >= 0) & (ix < WW))
                                    ? gbase[(size_t)(go * 8 + j) * HWSZ + (size_t)iy * WW + ix]
                                    : 0.f;
                            }
                    }
                    #pragma unroll
                    for (int t = 0; t < 4; ++t) {
                        int cc = 4 * qa - 2 + t;
                        if (cc >= 0 && cc < 66) {
                            u32x4 wvv;
                            wvv[0] = pk2bf(va[0].f[t], va[1].f[t]);
                            wvv[1] = pk2bf(va[2].f[t], va[3].f[t]);
                            wvv[2] = pk2bf(va[4].f[t], va[5].f[t]);
                            wvv[3] = pk2bf(va[6].f[t], va[7].f[t]);
                            unsigned off = ((unsigned)((rr * 66 + cc) * 4 + go) * 16u)
                                           ^ swzA(cc);
                            *(u32x4*)((char*)ldsA + off) = wvv;
                        }
                    }
                }
            }
            __syncthreads();

            // ---- compute: 9 taps x 2 s x 2 nj (36 MFMA)
            for (int tap = 0; tap < 9; ++tap) {
                int di = tap / 3, dj = tap - di * 3;
                short8v Bf[2];
                #pragma unroll
                for (int nj = 0; nj < 2; ++nj)
                    Bf[nj] = *(const short8v*)(ldsB +
                        (((size_t)tap * 2 + nj) * 32 + l31) * 16 + lhi * 8);
                int rrow = wv + di;
                #pragma unroll
                for (int s = 0; s < 2; ++s) {
                    int cc = s * 32 + l31 + dj;
                    unsigned off = ((unsigned)((rrow * 66 + cc) * 4 + ks * 2 + lhi) * 16u)
                                   ^ swzA(cc);
                    short8v a = *(const short8v*)((const char*)ldsA + off);
                    acc[s][0] = __builtin_amdgcn_mfma_f32_32x32x16_bf16(a, Bf[0], acc[s][0], 0, 0, 0);
                    acc[s][1] = __builtin_amdgcn_mfma_f32_32x32x16_bf16(a, Bf[1], acc[s][1], 0, 0, 0);
                }
            }
        }
    }

    int oy = oy0 + wv;
    if (oy < HP) {
        float bias0 = b_kgl[l31], bias1 = b_kgl[32 + l31];
        u16* kout = ker + (size_t)bi * HWPSZ * GCC;
        int ckl = l31 >> 4, idx = l31 & 15;
        #pragma unroll
        for (int s = 0; s < 2; ++s)
            #pragma unroll
            for (int r = 0; r < 16; ++r) {
                int pxc = x0 + s * 32 + (r & 3) + 8 * (r >> 2) + 4 * lhi;
                if (pxc < WP) {
                    size_t pix = (size_t)oy * WP + pxc;
                    kout[((size_t)ckl * HWPSZ + pix) * 16 + idx]       = f2bf(acc[s][0][r] + bias0);
                    kout[((size_t)(2 + ckl) * HWPSZ + pix) * 16 + idx] = f2bf(acc[s][1][r] + bias1);
                }
            }
    }
}

// ---------------- K6: k_mix — direct f32 data gather (no dataC) -----------
// Same prd layout/swizzle/box-sum/MFMA as R12. Delta: staging reads data
// octets as 8 coalesced plane-strided f32 loads (c2 = t/528 remap puts 64
// consecutive px in a wave), products bf16(ker) x f32(data).
__global__ __launch_bounds__(384) void k_mix(const float* __restrict__ data,
                                             const u16* __restrict__ ker,
                                             const u16* __restrict__ kccB,
                                             float* __restrict__ out,
                                             float* __restrict__ stats, int b0) {
    int xt = blockIdx.x, rt = blockIdx.y, bi = blockIdx.z;
    int b = b0 + bi;
    int w0 = xt * 64, oy0 = rt * 6;
    int tid = threadIdx.x, wv = tid >> 6, lane = tid & 63;
    int l31 = lane & 31, lhi = lane >> 5;

    __shared__ __align__(16) float prd[2 * 528 * 8];   // 33792 B
    __shared__ float bsum[64], bsq[64];

    if (tid < 64) { bsum[tid] = 0.f; bsq[tid] = 0.f; }

    const u16* kerb = ker + (size_t)bi * HWPSZ * GCC;
    const float* datb = data + (size_t)b * CINC * HWSZ;
    const u16* kcb  = kccB + (size_t)b * COUTC * CINC;

    f32x16 acc[2][2] = {};    // [nj(o-half)][s(px-half)]
    u32x4 kvr[3];
    float dvr[3][8];

#define MIX_LOAD(CK)                                                          \
    {                                                                         \
        _Pragma("unroll")                                                     \
        for (int it = 0; it < 3; ++it) {                                      \
            int t = tid + it * 384;                                           \
            if (t < 1056) {                                                   \
                int c2 = t >= 528 ? 1 : 0;                                    \
                int px = t - c2 * 528;                                        \
                int r = px / 66, cc = px - r * 66;                            \
                int u = oy0 + r, kcol = w0 + cc;                              \
                int iu = u - 1, iv = kcol - 1;                                \
                u32x4 kz = {0, 0, 0, 0};                                      \
                _Pragma("unroll")                                             \
                for (int j = 0; j < 8; ++j) dvr[it][j] = 0.f;                 \
                if (u < HP && iu >= 0 && iu < HH && iv >= 0 && iv < WW) {     \
                    kz = *(const u32x4*)(kerb + ((size_t)(CK) * HWPSZ + (size_t)u * WP + kcol) * 16 + c2 * 8); \
                    const float* dp = datb + ((size_t)(CK) * 16 + c2 * 8) * HWSZ + (size_t)iu * WW + iv; \
                    _Pragma("unroll")                                         \
                    for (int j = 0; j < 8; ++j) dvr[it][j] = dp[(size_t)j * HWSZ]; \
                }                                                             \
                kvr[it] = kz;                                                 \
            }                                                                 \
        }                                                                     \
    }

    MIX_LOAD(0);

    #pragma unroll
    for (int ck = 0; ck < 4; ++ck) {
        if (ck) __syncthreads();                 // prev compute done reading prd
        // ---- write staged regs -> prd (window-keyed XOR swizzle)
        #pragma unroll
        for (int it = 0; it < 3; ++it) {
            int t = tid + it * 384;
            if (t < 1056) {
                int c2 = t >= 528 ? 1 : 0;
                int px = t - c2 * 528;
                float pr[8];
                #pragma unroll
                for (int p = 0; p < 4; ++p) {
                    pr[2 * p]     = __uint_as_float(kvr[it][p] << 16) * dvr[it][2 * p];
                    pr[2 * p + 1] = __uint_as_float(kvr[it][p] & 0xffff0000u) * dvr[it][2 * p + 1];
                }
                unsigned fo = (unsigned)((c2 * 4224 + px * 8) * 4);
                unsigned x = swzP(px);
                *(float4*)((char*)prd + (fo ^ x))        = make_float4(pr[0], pr[1], pr[2], pr[3]);
                *(float4*)((char*)prd + ((fo + 16) ^ x)) = make_float4(pr[4], pr[5], pr[6], pr[7]);
            }
        }
        __syncthreads();
        if (ck < 3) MIX_LOAD(ck + 1);            // prefetch next chunk (T14)

        // ---- compute: box-sum from swizzled prd + MFMA mix
        short8v ka0 = *(const short8v*)(kcb + ((size_t)l31 * 64 + ck * 16 + lhi * 8));
        short8v ka1 = *(const short8v*)(kcb + ((size_t)(32 + l31) * 64 + ck * 16 + lhi * 8));

        #pragma unroll
        for (int s = 0; s < 2; ++s) {
            float x1v[8];
            #pragma unroll
            for (int j = 0; j < 8; ++j) x1v[j] = 0.f;
            #pragma unroll
            for (int di = 0; di < 3; ++di) {
                int row = wv + di;
                #pragma unroll
                for (int dj = 0; dj < 3; ++dj) {
                    int col = s * 32 + l31 + dj;
                    int px = row * 66 + col;
                    unsigned fo = (unsigned)((lhi * 4224 + px * 8) * 4);
                    unsigned x = swzP(px);
                    float4 a0 = *(const float4*)((const char*)prd + (fo ^ x));
                    float4 a1 = *(const float4*)((const char*)prd + ((fo + 16) ^ x));
                    x1v[0] += a0.x; x1v[1] += a0.y; x1v[2] += a0.z; x1v[3] += a0.w;
                    x1v[4] += a1.x; x1v[5] += a1.y; x1v[6] += a1.z; x1v[7] += a1.w;
                }
            }
            union { u16 h[8]; short8v v8; } xb;
            #pragma unroll
            for (int j = 0; j < 8; ++j) xb.h[j] = f2bf(x1v[j]);
            acc[0][s] = __builtin_amdgcn_mfma_f32_32x32x16_bf16(ka0, xb.v8, acc[0][s], 0, 0, 0);
            acc[1][s] = __builtin_amdgcn_mfma_f32_32x32x16_bf16(ka1, xb.v8, acc[1][s], 0, 0, 0);
        }
    }
#undef MIX_LOAD

    int oy = oy0 + wv;
    if (oy < HH) {
        #pragma unroll
        for (int nj = 0; nj < 2; ++nj)
            #pragma unroll
            for (int r = 0; r < 16; ++r) {
                int o = nj * 32 + (r & 3) + 8 * (r >> 2) + 4 * lhi;
                float v0 = acc[nj][0][r]; v0 = v0 > 0.f ? v0 : LEAK * v0;
                float v1 = acc[nj][1][r]; v1 = v1 > 0.f ? v1 : LEAK * v1;
                size_t rowb = ((size_t)(b * COUTC + o)) * HWSZ + (size_t)oy * WW + w0;
                out[rowb + l31]      = v0;
                out[rowb + 32 + l31] = v1;
                float ss = v0 + v1, qq = v0 * v0 + v1 * v1;
                #pragma unroll
                for (int off = 16; off; off >>= 1) {
                    ss += __shfl_xor(ss, off);
                    qq += __shfl_xor(qq, off);
                }
                if (l31 == 0) { atomicAdd(&bsum[o], ss); atomicAdd(&bsq[o], qq); }
            }
    }
    __syncthreads();
    int rep = (blockIdx.x + blockIdx.y * 5 + blockIdx.z * 3) & 7;
    if (tid < 64) {
        atomicAdd(&stats[rep * 128 + tid], bsum[tid]);
        atomicAdd(&stats[rep * 128 + 64 + tid], bsq[tid]);
    }
}

__global__ void k_fin(const float* __restrict__ stats,
                      const float* __restrict__ gamma, const float* __restrict__ beta,
                      float* __restrict__ scale, float* __restrict__ shift) {
    int o = threadIdx.x;
    float s = 0.f, q = 0.f;
    #pragma unroll
    for (int r = 0; r < 8; ++r) { s += stats[r * 128 + o]; q += stats[r * 128 + 64 + o]; }
    float n = (float)BB * (float)HWSZ;
    float mu = s / n;
    float var = q / n - mu * mu;
    float rs = rsqrtf(var + EPSB);
    float sc = rs * gamma[o];
    scale[o] = sc;
    shift[o] = beta[o] - mu * sc;
}

__global__ __launch_bounds__(256) void k_norm(float* __restrict__ x,
                                              const float* __restrict__ scale,
                                              const float* __restrict__ shift) {
    size_t i = (size_t)blockIdx.x * 256 + threadIdx.x;
    int ch = (int)((i * 4) / HWSZ) & 63;
    float4 v = ((float4*)x)[i];
    float sc = scale[ch], sh = shift[ch];
    v.x = v.x * sc + sh; v.y = v.y * sc + sh; v.z = v.z * sc + sh; v.w = v.w * sc + sh;
    ((float4*)x)[i] = v;
}

extern "C" void kernel_launch(void* const* d_in, const int* in_sizes, int n_in,
                              void* d_out, int out_size, void* d_ws, size_t ws_size,
                              hipStream_t stream) {
    const float* data  = (const float*)d_in[0];
    const float* guid  = (const float*)d_in[1];
    const float* w_kgl = (const float*)d_in[2];
    const float* b_kgl = (const float*)d_in[3];
    const float* w_cc  = (const float*)d_in[4];
    const float* b_cc  = (const float*)d_in[5];
    const float* gamma = (const float*)d_in[6];
    const float* beta  = (const float*)d_in[7];
    float* out = (float*)d_out;
    float* ws  = (float*)d_ws;

    // ws (f32): [mean_g 512][stats 8*128][scale 64][shift 64] = 1664
    // then u16: [kccB 32768][wB 36864][kerC bs*HWPSZ*64]
    float* mean_g = ws;
    float* stats  = ws + 512;
    float* scale  = stats + 1024;
    float* shift  = scale + 64;
    u16*   kccB   = (u16*)(ws + 1664);
    u16*   wB     = kccB + BB * 4096;
    u16*   kerC   = wB + 36864;

    size_t used_us = 1664 * 2 + BB * 4096 + 36864;
    size_t cap_us  = (ws_size / 2 > used_us) ? ws_size / 2 - used_us : 0;
    size_t per_b   = (size_t)HWPSZ * GCC;
    // bs=4: kerC chunk = 53 MB, L3-resident between k_convm and k_mix
    int bs = 4;
    while (bs > 1 && (size_t)bs * per_b > cap_us) bs >>= 1;

    hipMemsetAsync(stats, 0, 1024 * sizeof(float), stream);
    k_mean<<<BB * GCC, 256, 0, stream>>>(guid, mean_g);
    k_kcc<<<(BB * COUTC * CINC + 255) / 256, 256, 0, stream>>>(mean_g, w_cc, b_cc, kccB);
    k_wb<<<144, 256, 0, stream>>>(w_kgl, wB);

    for (int b0 = 0; b0 < BB; b0 += bs) {
        int nb = (BB - b0 < bs) ? BB - b0 : bs;
        k_convm<<<dim3(6, 54, nb), 384, 0, stream>>>(guid, wB, b_kgl, kerC, b0);
        k_mix<<<dim3(5, 54, nb), 384, 0, stream>>>(data, kerC, kccB, out, stats, b0);
    }
    k_fin<<<1, 64, 0, stream>>>(stats, gamma, beta, scale, shift);
    k_norm<<<(out_size / 4 + 255) / 256, 256, 0, stream>>>(out, scale, shift);
}

// Round 14
// 551.781 us; speedup vs baseline: 6.3054x; 1.0510x over previous
//
#include <hip/hip_runtime.h>

#define BB 8
#define CINC 64
#define COUTC 64
#define GCC 64
#define HH 320
#define WW 320
#define HP 322
#define WP 322
#define LEAK 0.2f
#define EPSB 1e-5f
#define HWSZ (HH*WW)
#define HWPSZ (HP*WP)

typedef unsigned short u16;
typedef __attribute__((ext_vector_type(8))) short short8v;   // 8 bf16
typedef __attribute__((ext_vector_type(16))) float f32x16;   // MFMA 32x32 acc
typedef __attribute__((ext_vector_type(4))) unsigned int u32x4;

static __device__ __forceinline__ u16 f2bf(float f) {
    unsigned u = __float_as_uint(f);
    u += 0x7fffu + ((u >> 16) & 1u);      // RNE
    return (u16)(u >> 16);
}
static __device__ __forceinline__ unsigned pk2bf(float a, float b) {
    return (unsigned)f2bf(a) | ((unsigned)f2bf(b) << 16);
}
// A-tile LDS swizzle (R6/R7-verified key)
static __device__ __forceinline__ unsigned swzA(int cc) {
    return (unsigned)((((cc >> 1) & 1) << 5) | (((cc >> 2) & 1) << 4));
}
// prd swizzle key: window-indexed, bijective by construction (R12-verified)
static __device__ __forceinline__ unsigned swzP(int px) {
    return ((unsigned)(px >> 2) & 7u) << 4;
}

// ---------------- K1: per-(b,g) mean of guidance ----------------
__global__ __launch_bounds__(256) void k_mean(const float* __restrict__ g,
                                              float* __restrict__ mean_g) {
    int row = blockIdx.x;                       // b*GC + gc
    const float4* p = (const float4*)(g + (size_t)row * HWSZ);
    float s = 0.f;
    for (int i = threadIdx.x; i < HWSZ / 4; i += 256) {
        float4 v = p[i];
        s += v.x + v.y + v.z + v.w;
    }
    #pragma unroll
    for (int off = 32; off; off >>= 1) s += __shfl_down(s, off);
    __shared__ float ls[4];
    if ((threadIdx.x & 63) == 0) ls[threadIdx.x >> 6] = s;
    __syncthreads();
    if (threadIdx.x == 0)
        mean_g[row] = (ls[0] + ls[1] + ls[2] + ls[3]) * (1.f / (float)HWSZ);
}

// ---------------- K2: kccB[b][o][c] bf16 ----------------
__global__ __launch_bounds__(256) void k_kcc(const float* __restrict__ mean_g,
                                             const float* __restrict__ w_cc,
                                             const float* __restrict__ b_cc,
                                             u16* __restrict__ kccB) {
    int idx = blockIdx.x * 256 + threadIdx.x;
    if (idx >= BB * COUTC * CINC) return;
    int b = idx >> 12;
    int j = idx & 4095;                  // o*64 + c
    const float* mg = mean_g + b * GCC;
    const float* wr = w_cc + (size_t)j * GCC;
    float s = b_cc[j];
    #pragma unroll
    for (int g = 0; g < GCC; ++g) s += mg[g] * wr[g];
    kccB[idx] = f2bf(s);
}

// ---------------- K3: wB = LDS image [gc][ks][tap][nj][l31][lhi][j] -------
__global__ __launch_bounds__(256) void k_wb(const float* __restrict__ w_kgl,
                                            u16* __restrict__ wB) {
    int idx = blockIdx.x * 256 + threadIdx.x;
    if (idx >= 36864) return;
    int j   = idx & 7;
    int lhi = (idx >> 3) & 1;
    int l   = (idx >> 4) & 31;
    int nj  = (idx >> 9) & 1;
    int t   = idx >> 10;          // (gc*2+ks)*9 + tap
    int tap = t % 9, gk = t / 9;
    int ks = gk & 1, gc = gk >> 1;
    int cout = nj * 32 + l;
    int g = gc * 32 + ks * 16 + lhi * 8 + j;
    wB[idx] = f2bf(w_kgl[((size_t)(cout * 64 + g)) * 9 + tap]);
}

// ---------------- K5: MFMA conv, A staged from RAW guid (R10-verified) ----
__global__ __launch_bounds__(384) void k_convm(const float* __restrict__ guid,
                                               const u16* __restrict__ wB,
                                               const float* __restrict__ b_kgl,
                                               u16* __restrict__ ker, int b0) {
    int xt = blockIdx.x, rt = blockIdx.y, bi = blockIdx.z;
    int bg = b0 + bi;
    int tid = threadIdx.x;
    int x0 = xt * 64, oy0 = rt * 6;
    __shared__ __align__(16) u16 ldsA[8 * 66 * 32];        // 33792 B
    __shared__ __align__(16) u16 ldsB[9 * 2 * 32 * 16];    // 18432 B

    int wv = tid >> 6, lane = tid & 63;
    int l31 = lane & 31, lhi = lane >> 5;
    f32x16 acc[2][2] = {};    // [s(px-half)][nj(cout-half)]

    for (int gc = 0; gc < 2; ++gc) {
        for (int ks = 0; ks < 2; ++ks) {
            if (gc | ks) __syncthreads();
            // ---- stage B: linear 18432 B copy
            const u16* bsrc = wB + (gc * 2 + ks) * 9216;
            #pragma unroll
            for (int k = 0; k < 3; ++k) {
                int i = tid + k * 384;
                *(u32x4*)(ldsB + (size_t)i * 8) = *(const u32x4*)(bsrc + (size_t)i * 8);
            }
            // ---- stage A from RAW guidance f32 (fused transpose + pack)
            if (ks == 0) {
                const float* gbase = guid + ((size_t)bg * 64 + gc * 32) * HWSZ;
                for (int i = tid; i < 544; i += 384) {
                    int qa = i % 17;
                    int rem = i / 17;
                    int go = rem & 3, rr = rem >> 2;
                    int iy = oy0 - 2 + rr;
                    int ix0 = x0 - 4 + 4 * qa;
                    union { float4 q; float f[4]; } va[8];
                    bool rowok = (iy >= 0) & (iy < HH);
                    if (rowok & (ix0 >= 0) & (ix0 + 3 < WW)) {
                        #pragma unroll
                        for (int j = 0; j < 8; ++j)
                            va[j].q = *(const float4*)(gbase + (size_t)(go * 8 + j) * HWSZ
                                                       + (size_t)iy * WW + ix0);
                    } else {
                        #pragma unroll
                        for (int j = 0; j < 8; ++j)
                            #pragma unroll
                            for (int t = 0; t < 4; ++t) {
                                int ix = ix0 + t;
                                va[j].f[t] = (rowok & (ix >= 0) & (ix < WW))
                                    ? gbase[(size_t)(go * 8 + j) * HWSZ + (size_t)iy * WW + ix]
                                    : 0.f;
                            }
                    }
                    #pragma unroll
                    for (int t = 0; t < 4; ++t) {
                        int cc = 4 * qa - 2 + t;
                        if (cc >= 0 && cc < 66) {
                            u32x4 wvv;
                            wvv[0] = pk2bf(va[0].f[t], va[1].f[t]);
                            wvv[1] = pk2bf(va[2].f[t], va[3].f[t]);
                            wvv[2] = pk2bf(va[4].f[t], va[5].f[t]);
                            wvv[3] = pk2bf(va[6].f[t], va[7].f[t]);
                            unsigned off = ((unsigned)((rr * 66 + cc) * 4 + go) * 16u)
                                           ^ swzA(cc);
                            *(u32x4*)((char*)ldsA + off) = wvv;
                        }
                    }
                }
            }
            __syncthreads();

            // ---- compute: 9 taps x 2 s x 2 nj (36 MFMA)
            for (int tap = 0; tap < 9; ++tap) {
                int di = tap / 3, dj = tap - di * 3;
                short8v Bf[2];
                #pragma unroll
                for (int nj = 0; nj < 2; ++nj)
                    Bf[nj] = *(const short8v*)(ldsB +
                        (((size_t)tap * 2 + nj) * 32 + l31) * 16 + lhi * 8);
                int rrow = wv + di;
                #pragma unroll
                for (int s = 0; s < 2; ++s) {
                    int cc = s * 32 + l31 + dj;
                    unsigned off = ((unsigned)((rrow * 66 + cc) * 4 + ks * 2 + lhi) * 16u)
                                   ^ swzA(cc);
                    short8v a = *(const short8v*)((const char*)ldsA + off);
                    acc[s][0] = __builtin_amdgcn_mfma_f32_32x32x16_bf16(a, Bf[0], acc[s][0], 0, 0, 0);
                    acc[s][1] = __builtin_amdgcn_mfma_f32_32x32x16_bf16(a, Bf[1], acc[s][1], 0, 0, 0);
                }
            }
        }
    }

    int oy = oy0 + wv;
    if (oy < HP) {
        float bias0 = b_kgl[l31], bias1 = b_kgl[32 + l31];
        u16* kout = ker + (size_t)bi * HWPSZ * GCC;
        int ckl = l31 >> 4, idx = l31 & 15;
        #pragma unroll
        for (int s = 0; s < 2; ++s)
            #pragma unroll
            for (int r = 0; r < 16; ++r) {
                int pxc = x0 + s * 32 + (r & 3) + 8 * (r >> 2) + 4 * lhi;
                if (pxc < WP) {
                    size_t pix = (size_t)oy * WP + pxc;
                    kout[((size_t)ckl * HWPSZ + pix) * 16 + idx]       = f2bf(acc[s][0][r] + bias0);
                    kout[((size_t)(2 + ckl) * HWPSZ + pix) * 16 + idx] = f2bf(acc[s][1][r] + bias1);
                }
            }
    }
}

// ---------------- K6: k_mix — 4-wave blocks, product-reg staging ----------
// Same math/swizzle as R13; tile is 4 output rows (prd 6 rows x 66 cols),
// 256 threads -> 4 blocks/CU occupancy. Staging computes products directly
// into pvr (no kvr/dvr split) to hold VGPR <= 128.
__global__ __launch_bounds__(256) void k_mix(const float* __restrict__ data,
                                             const u16* __restrict__ ker,
                                             const u16* __restrict__ kccB,
                                             float* __restrict__ out,
                                             float* __restrict__ stats, int b0) {
    int xt = blockIdx.x, rt = blockIdx.y, bi = blockIdx.z;
    int b = b0 + bi;
    int w0 = xt * 64, oy0 = rt * 4;
    int tid = threadIdx.x, wv = tid >> 6, lane = tid & 63;
    int l31 = lane & 31, lhi = lane >> 5;

    __shared__ __align__(16) float prd[2 * 396 * 8];   // 25344 B
    __shared__ float bsum[64], bsq[64];

    if (tid < 64) { bsum[tid] = 0.f; bsq[tid] = 0.f; }

    const u16* kerb = ker + (size_t)bi * HWPSZ * GCC;
    const float* datb = data + (size_t)b * CINC * HWSZ;
    const u16* kcb  = kccB + (size_t)b * COUTC * CINC;

    f32x16 acc[2][2] = {};    // [nj(o-half)][s(px-half)]
    float pvr[4][8];          // staged PRODUCTS for next chunk

#define MIX_LOAD(CK)                                                          \
    {                                                                         \
        _Pragma("unroll")                                                     \
        for (int it = 0; it < 4; ++it) {                                      \
            int t = tid + it * 256;                                           \
            if (t < 792) {                                                    \
                int c2 = t >= 396 ? 1 : 0;                                    \
                int px = t - c2 * 396;                                        \
                int r = px / 66, cc = px - r * 66;                            \
                int u = oy0 + r, kcol = w0 + cc;                              \
                int iu = u - 1, iv = kcol - 1;                                \
                _Pragma("unroll")                                             \
                for (int j = 0; j < 8; ++j) pvr[it][j] = 0.f;                 \
                if (u < HP && iu >= 0 && iu < HH && iv >= 0 && iv < WW) {     \
                    u32x4 kz = *(const u32x4*)(kerb + ((size_t)(CK) * HWPSZ + (size_t)u * WP + kcol) * 16 + c2 * 8); \
                    const float* dp = datb + ((size_t)(CK) * 16 + c2 * 8) * HWSZ + (size_t)iu * WW + iv; \
                    _Pragma("unroll")                                         \
                    for (int p = 0; p < 4; ++p) {                             \
                        pvr[it][2 * p]     = __uint_as_float(kz[p] << 16) * dp[(size_t)(2 * p) * HWSZ];       \
                        pvr[it][2 * p + 1] = __uint_as_float(kz[p] & 0xffff0000u) * dp[(size_t)(2 * p + 1) * HWSZ]; \
                    }                                                         \
                }                                                             \
            }                                                                 \
        }                                                                     \
    }

    MIX_LOAD(0);

    #pragma unroll
    for (int ck = 0; ck < 4; ++ck) {
        if (ck) __syncthreads();                 // prev compute done reading prd
        // ---- write staged products -> prd (window-keyed XOR swizzle)
        #pragma unroll
        for (int it = 0; it < 4; ++it) {
            int t = tid + it * 256;
            if (t < 792) {
                int c2 = t >= 396 ? 1 : 0;
                int px = t - c2 * 396;
                unsigned fo = (unsigned)((c2 * 3168 + px * 8) * 4);
                unsigned x = swzP(px);
                *(float4*)((char*)prd + (fo ^ x))        = make_float4(pvr[it][0], pvr[it][1], pvr[it][2], pvr[it][3]);
                *(float4*)((char*)prd + ((fo + 16) ^ x)) = make_float4(pvr[it][4], pvr[it][5], pvr[it][6], pvr[it][7]);
            }
        }
        __syncthreads();
        if (ck < 3) MIX_LOAD(ck + 1);            // prefetch next chunk (T14)

        // ---- compute: box-sum from swizzled prd + MFMA mix
        short8v ka0 = *(const short8v*)(kcb + ((size_t)l31 * 64 + ck * 16 + lhi * 8));
        short8v ka1 = *(const short8v*)(kcb + ((size_t)(32 + l31) * 64 + ck * 16 + lhi * 8));

        #pragma unroll
        for (int s = 0; s < 2; ++s) {
            float x1v[8];
            #pragma unroll
            for (int j = 0; j < 8; ++j) x1v[j] = 0.f;
            #pragma unroll
            for (int di = 0; di < 3; ++di) {
                int row = wv + di;
                #pragma unroll
                for (int dj = 0; dj < 3; ++dj) {
                    int col = s * 32 + l31 + dj;
                    int px = row * 66 + col;
                    unsigned fo = (unsigned)((lhi * 3168 + px * 8) * 4);
                    unsigned x = swzP(px);
                    float4 a0 = *(const float4*)((const char*)prd + (fo ^ x));
                    float4 a1 = *(const float4*)((const char*)prd + ((fo + 16) ^ x));
                    x1v[0] += a0.x; x1v[1] += a0.y; x1v[2] += a0.z; x1v[3] += a0.w;
                    x1v[4] += a1.x; x1v[5] += a1.y; x1v[6] += a1.z; x1v[7] += a1.w;
                }
            }
            union { u16 h[8]; short8v v8; } xb;
            #pragma unroll
            for (int j = 0; j < 8; ++j) xb.h[j] = f2bf(x1v[j]);
            acc[0][s] = __builtin_amdgcn_mfma_f32_32x32x16_bf16(ka0, xb.v8, acc[0][s], 0, 0, 0);
            acc[1][s] = __builtin_amdgcn_mfma_f32_32x32x16_bf16(ka1, xb.v8, acc[1][s], 0, 0, 0);
        }
    }
#undef MIX_LOAD

    int oy = oy0 + wv;
    if (oy < HH) {
        #pragma unroll
        for (int nj = 0; nj < 2; ++nj)
            #pragma unroll
            for (int r = 0; r < 16; ++r) {
                int o = nj * 32 + (r & 3) + 8 * (r >> 2) + 4 * lhi;
                float v0 = acc[nj][0][r]; v0 = v0 > 0.f ? v0 : LEAK * v0;
                float v1 = acc[nj][1][r]; v1 = v1 > 0.f ? v1 : LEAK * v1;
                size_t rowb = ((size_t)(b * COUTC + o)) * HWSZ + (size_t)oy * WW + w0;
                out[rowb + l31]      = v0;
                out[rowb + 32 + l31] = v1;
                float ss = v0 + v1, qq = v0 * v0 + v1 * v1;
                #pragma unroll
                for (int off = 16; off; off >>= 1) {
                    ss += __shfl_xor(ss, off);
                    qq += __shfl_xor(qq, off);
                }
                if (l31 == 0) { atomicAdd(&bsum[o], ss); atomicAdd(&bsq[o], qq); }
            }
    }
    __syncthreads();
    int rep = (blockIdx.x + blockIdx.y * 5 + blockIdx.z * 3) & 7;
    if (tid < 64) {
        atomicAdd(&stats[rep * 128 + tid], bsum[tid]);
        atomicAdd(&stats[rep * 128 + 64 + tid], bsq[tid]);
    }
}

__global__ void k_fin(const float* __restrict__ stats,
                      const float* __restrict__ gamma, const float* __restrict__ beta,
                      float* __restrict__ scale, float* __restrict__ shift) {
    int o = threadIdx.x;
    float s = 0.f, q = 0.f;
    #pragma unroll
    for (int r = 0; r < 8; ++r) { s += stats[r * 128 + o]; q += stats[r * 128 + 64 + o]; }
    float n = (float)BB * (float)HWSZ;
    float mu = s / n;
    float var = q / n - mu * mu;
    float rs = rsqrtf(var + EPSB);
    float sc = rs * gamma[o];
    scale[o] = sc;
    shift[o] = beta[o] - mu * sc;
}

__global__ __launch_bounds__(256) void k_norm(float* __restrict__ x,
                                              const float* __restrict__ scale,
                                              const float* __restrict__ shift) {
    size_t i = (size_t)blockIdx.x * 256 + threadIdx.x;
    int ch = (int)((i * 4) / HWSZ) & 63;
    float4 v = ((float4*)x)[i];
    float sc = scale[ch], sh = shift[ch];
    v.x = v.x * sc + sh; v.y = v.y * sc + sh; v.z = v.z * sc + sh; v.w = v.w * sc + sh;
    ((float4*)x)[i] = v;
}

extern "C" void kernel_launch(void* const* d_in, const int* in_sizes, int n_in,
                              void* d_out, int out_size, void* d_ws, size_t ws_size,
                              hipStream_t stream) {
    const float* data  = (const float*)d_in[0];
    const float* guid  = (const float*)d_in[1];
    const float* w_kgl = (const float*)d_in[2];
    const float* b_kgl = (const float*)d_in[3];
    const float* w_cc  = (const float*)d_in[4];
    const float* b_cc  = (const float*)d_in[5];
    const float* gamma = (const float*)d_in[6];
    const float* beta  = (const float*)d_in[7];
    float* out = (float*)d_out;
    float* ws  = (float*)d_ws;

    // ws (f32): [mean_g 512][stats 8*128][scale 64][shift 64] = 1664
    // then u16: [kccB 32768][wB 36864][kerC bs*HWPSZ*64]
    float* mean_g = ws;
    float* stats  = ws + 512;
    float* scale  = stats + 1024;
    float* shift  = scale + 64;
    u16*   kccB   = (u16*)(ws + 1664);
    u16*   wB     = kccB + BB * 4096;
    u16*   kerC   = wB + 36864;

    size_t used_us = 1664 * 2 + BB * 4096 + 36864;
    size_t cap_us  = (ws_size / 2 > used_us) ? ws_size / 2 - used_us : 0;
    size_t per_b   = (size_t)HWPSZ * GCC;
    // bs=8: kerC = 106 MB total, L3-resident between k_convm and k_mix
    int bs = 8;
    while (bs > 1 && (size_t)bs * per_b > cap_us) bs >>= 1;

    hipMemsetAsync(stats, 0, 1024 * sizeof(float), stream);
    k_mean<<<BB * GCC, 256, 0, stream>>>(guid, mean_g);
    k_kcc<<<(BB * COUTC * CINC + 255) / 256, 256, 0, stream>>>(mean_g, w_cc, b_cc, kccB);
    k_wb<<<144, 256, 0, stream>>>(w_kgl, wB);

    for (int b0 = 0; b0 < BB; b0 += bs) {
        int nb = (BB - b0 < bs) ? BB - b0 : bs;
        k_convm<<<dim3(6, 54, nb), 384, 0, stream>>>(guid, wB, b_kgl, kerC, b0);
        k_mix<<<dim3(5, 80, nb), 256, 0, stream>>>(data, kerC, kccB, out, stats, b0);
    }
    k_fin<<<1, 64, 0, stream>>>(stats, gamma, beta, scale, shift);
    k_norm<<<(out_size / 4 + 255) / 256, 256, 0, stream>>>(out, scale, shift);
}